// Round 1
// baseline (7308.775 us; speedup 1.0000x reference)
//
#include <hip/hip_runtime.h>

#define NEG_SLOPE 0.2f

// ---------------- generic tiled SGEMM: C = act(concat(U,V) @ W + bias) ----------------
// A = [U | V] row-major, U: [rows,K1], V: [rows,K2] (V may be null, K2=0)
// W: [K1+K2, Mo] row-major.  act: 0=none, 1=sigmoid
__global__ __launch_bounds__(256) void gemm_k(
    const float* __restrict__ U, int K1,
    const float* __restrict__ V, int K2,
    const float* __restrict__ W, const float* __restrict__ bias,
    float* __restrict__ Cout, int rows, int Mo, int act)
{
    __shared__ float As[16][65];
    __shared__ float Bs[16][64];
    const int tid = threadIdx.x;
    const int row0 = blockIdx.y * 64;
    const int col0 = blockIdx.x * 64;
    const int tx = tid & 15, ty = tid >> 4;
    const int K = K1 + K2;
    float acc[4][4] = {};
    for (int k0 = 0; k0 < K; k0 += 16) {
#pragma unroll
        for (int i = 0; i < 4; ++i) {
            int idx = tid + i * 256;
            int rl = idx >> 4, kl = idx & 15;
            int r = row0 + rl, k = k0 + kl;
            float v = 0.f;
            if (r < rows) {
                if (k < K1) v = U[(long)r * K1 + k];
                else        v = V[(long)r * K2 + (k - K1)];
            }
            As[kl][rl] = v;
        }
#pragma unroll
        for (int i = 0; i < 4; ++i) {
            int idx = tid + i * 256;
            int kl = idx >> 6, jl = idx & 63;
            Bs[kl][jl] = W[(long)(k0 + kl) * Mo + (col0 + jl)];
        }
        __syncthreads();
#pragma unroll
        for (int k = 0; k < 16; ++k) {
            float a[4], b[4];
#pragma unroll
            for (int i = 0; i < 4; ++i) a[i] = As[k][ty * 4 + i];
#pragma unroll
            for (int j = 0; j < 4; ++j) b[j] = Bs[k][tx * 4 + j];
#pragma unroll
            for (int i = 0; i < 4; ++i)
#pragma unroll
                for (int j = 0; j < 4; ++j)
                    acc[i][j] += a[i] * b[j];
        }
        __syncthreads();
    }
#pragma unroll
    for (int i = 0; i < 4; ++i) {
        int r = row0 + ty * 4 + i;
        if (r >= rows) continue;
#pragma unroll
        for (int j = 0; j < 4; ++j) {
            int c = col0 + tx * 4 + j;
            float v = acc[i][j] + (bias ? bias[c] : 0.f);
            if (act == 1) v = 1.f / (1.f + __expf(-v));
            Cout[(long)r * Mo + c] = v;
        }
    }
}

// ---------------- fused GRU: z-GEMM + hhat-GEMM + output elementwise ----------------
// A_z = [G | Hin], A_h = [G | R*Hin]; Out = (1-z)*Hin + z*tanh(acch+bh)
__global__ __launch_bounds__(256) void gru_fused_k(
    const float* __restrict__ Gp, const float* __restrict__ Hin,
    const float* __restrict__ Rp, int D,
    const float* __restrict__ Wz, const float* __restrict__ bz,
    const float* __restrict__ Wh, const float* __restrict__ bh,
    float* __restrict__ Out, int rows)
{
    __shared__ float Az[16][65];
    __shared__ float Ah[16][65];
    __shared__ float Bz[16][64];
    __shared__ float Bh[16][64];
    const int tid = threadIdx.x;
    const int row0 = blockIdx.y * 64;
    const int col0 = blockIdx.x * 64;
    const int tx = tid & 15, ty = tid >> 4;
    const int K = 2 * D;
    float accz[4][4] = {}, acch[4][4] = {};
    for (int k0 = 0; k0 < K; k0 += 16) {
#pragma unroll
        for (int i = 0; i < 4; ++i) {
            int idx = tid + i * 256;
            int rl = idx >> 4, kl = idx & 15;
            int r = row0 + rl, k = k0 + kl;
            float vz = 0.f, vh = 0.f;
            if (r < rows) {
                if (k < D) { vz = Gp[(long)r * D + k]; vh = vz; }
                else {
                    int k2 = k - D;
                    float hv = Hin[(long)r * D + k2];
                    vz = hv; vh = hv * Rp[(long)r * D + k2];
                }
            }
            Az[kl][rl] = vz; Ah[kl][rl] = vh;
        }
#pragma unroll
        for (int i = 0; i < 4; ++i) {
            int idx = tid + i * 256;
            int kl = idx >> 6, jl = idx & 63;
            Bz[kl][jl] = Wz[(long)(k0 + kl) * D + (col0 + jl)];
            Bh[kl][jl] = Wh[(long)(k0 + kl) * D + (col0 + jl)];
        }
        __syncthreads();
#pragma unroll
        for (int k = 0; k < 16; ++k) {
            float az[4], ah[4], bzv[4], bhv[4];
#pragma unroll
            for (int i = 0; i < 4; ++i) { az[i] = Az[k][ty * 4 + i]; ah[i] = Ah[k][ty * 4 + i]; }
#pragma unroll
            for (int j = 0; j < 4; ++j) { bzv[j] = Bz[k][tx * 4 + j]; bhv[j] = Bh[k][tx * 4 + j]; }
#pragma unroll
            for (int i = 0; i < 4; ++i)
#pragma unroll
                for (int j = 0; j < 4; ++j) {
                    accz[i][j] += az[i] * bzv[j];
                    acch[i][j] += ah[i] * bhv[j];
                }
        }
        __syncthreads();
    }
#pragma unroll
    for (int i = 0; i < 4; ++i) {
        int r = row0 + ty * 4 + i;
        if (r >= rows) continue;
#pragma unroll
        for (int j = 0; j < 4; ++j) {
            int c = col0 + tx * 4 + j;
            float z = 1.f / (1.f + __expf(-(accz[i][j] + bz[c])));
            float hh = tanhf(acch[i][j] + bh[c]);
            float hv = Hin[(long)r * D + c];
            Out[(long)r * D + c] = (1.f - z) * hv + z * hh;
        }
    }
}

// ---------------- alpha_s / alpha_d per (node, head) ----------------
__global__ void alpha_k(const float* __restrict__ XP,
                        const float* __restrict__ a_s, const float* __restrict__ a_d,
                        float* __restrict__ AS, float* __restrict__ AD,
                        int Nn, int H, int C)
{
    int i = blockIdx.x * blockDim.x + threadIdx.x;
    if (i >= Nn * H) return;
    int n = i / H, h = i % H;
    const float* xp = &XP[(long)n * H * C + (long)h * C];
    float ss = 0.f, sd = 0.f;
    for (int c = 0; c < C; ++c) {
        float v = xp[c];
        ss += v * a_s[h * C + c];
        sd += v * a_d[h * C + c];
    }
    AS[i] = ss; AD[i] = sd;
}

// ---------------- edge pass 1: softmax denominator (no max-shift; logits are O(1)) ----
__global__ void edge_denom(const int* __restrict__ src, const int* __restrict__ dst,
                           int E, int Nn, int H,
                           const float* __restrict__ AS, const float* __restrict__ AD,
                           float* __restrict__ DEN)
{
    int e = blockIdx.x * blockDim.x + threadIdx.x;
    int ET = E + Nn;
    if (e >= ET) return;
    int s = e < E ? src[e] : e - E;
    int d = e < E ? dst[e] : e - E;
    for (int h = 0; h < H; ++h) {
        float v = AS[s * H + h] + AD[d * H + h];
        v = v > 0.f ? v : NEG_SLOPE * v;
        atomicAdd(&DEN[d * H + h], __expf(v));
    }
}

// ---------------- edge pass 2: weighted aggregation (wave-cooperative, float4) -------
__global__ void edge_agg(const int* __restrict__ src, const int* __restrict__ dst,
                         int E, int Nn, int H, int C,
                         const float* __restrict__ XP,
                         const float* __restrict__ AS, const float* __restrict__ AD,
                         const float* __restrict__ DEN,
                         float* __restrict__ G)
{
    const int D = H * C;
    const int ch4 = D >> 2;        // lanes per edge
    const int epw = 64 / ch4;      // edges per wave
    int lane = threadIdx.x & 63;
    long wave = ((long)blockIdx.x * blockDim.x + threadIdx.x) >> 6;
    int sub = lane / ch4;
    int cl = lane % ch4;
    long e = wave * epw + sub;
    long ET = (long)E + Nn;
    if (e >= ET) return;
    int s = e < E ? src[e] : (int)(e - E);
    int d = e < E ? dst[e] : (int)(e - E);
    int j = cl * 4;
    int h = j / C;
    float v = AS[s * H + h] + AD[d * H + h];
    v = v > 0.f ? v : NEG_SLOPE * v;
    float w = __expf(v) / (DEN[d * H + h] + 1e-16f);
    float4 xv = *(const float4*)&XP[(long)s * D + j];
    float* gp = &G[(long)d * D + j];
    atomicAdd(gp + 0, xv.x * w);
    atomicAdd(gp + 1, xv.y * w);
    atomicAdd(gp + 2, xv.z * w);
    atomicAdd(gp + 3, xv.w * w);
}

// ---------------- bias + optional ELU ----------------
__global__ void bias_act(float* __restrict__ Gd, const float* __restrict__ b,
                         long n, int D, int do_elu)
{
    long i = (long)blockIdx.x * blockDim.x + threadIdx.x;
    if (i >= n) return;
    float v = Gd[i] + b[i % D];
    if (do_elu) v = v > 0.f ? v : expm1f(v);
    Gd[i] = v;
}

static inline void launch_edge_agg(const int* srcp, const int* dstp, int E, int Nn,
                                   int H, int C, const float* XP, const float* AS,
                                   const float* AD, const float* DEN, float* G,
                                   hipStream_t stream)
{
    int D = H * C;
    int ch4 = D >> 2;
    int epw = 64 / ch4;
    long ET = (long)E + Nn;
    long waves = (ET + epw - 1) / epw;
    long thr = waves * 64;
    int blocks = (int)((thr + 255) / 256);
    edge_agg<<<blocks, 256, 0, stream>>>(srcp, dstp, E, Nn, H, C, XP, AS, AD, DEN, G);
}

extern "C" void kernel_launch(void* const* d_in, const int* in_sizes, int n_in,
                              void* d_out, int out_size, void* d_ws, size_t ws_size,
                              hipStream_t stream)
{
    const float* x    = (const float*)d_in[0];
    const int*   ei   = (const int*)  d_in[1];
    const float* W_tr = (const float*)d_in[2];
    const float* b_tr = (const float*)d_in[3];
    const float* W1   = (const float*)d_in[4];
    const float* as1  = (const float*)d_in[5];
    const float* ad1  = (const float*)d_in[6];
    const float* b1   = (const float*)d_in[7];
    const float* Wr1  = (const float*)d_in[8];
    const float* br1  = (const float*)d_in[9];
    const float* Wz1  = (const float*)d_in[10];
    const float* bz1  = (const float*)d_in[11];
    const float* Wh1  = (const float*)d_in[12];
    const float* bh1  = (const float*)d_in[13];
    const float* Wp2  = (const float*)d_in[14];
    const float* bp2  = (const float*)d_in[15];
    const float* W2   = (const float*)d_in[16];
    const float* as2  = (const float*)d_in[17];
    const float* ad2  = (const float*)d_in[18];
    const float* b2   = (const float*)d_in[19];
    const float* Wr2  = (const float*)d_in[20];
    const float* br2  = (const float*)d_in[21];
    const float* Wz2  = (const float*)d_in[22];
    const float* bz2  = (const float*)d_in[23];
    const float* Wh2  = (const float*)d_in[24];
    const float* bh2  = (const float*)d_in[25];
    const float* Wp3  = (const float*)d_in[26];
    const float* bp3  = (const float*)d_in[27];
    const float* W3   = (const float*)d_in[28];
    const float* as3  = (const float*)d_in[29];
    const float* ad3  = (const float*)d_in[30];
    const float* b3   = (const float*)d_in[31];
    const float* Wr3  = (const float*)d_in[32];
    const float* br3  = (const float*)d_in[33];
    const float* Wz3  = (const float*)d_in[34];
    const float* bz3  = (const float*)d_in[35];
    const float* Wh3  = (const float*)d_in[36];
    const float* bh3  = (const float*)d_in[37];

    const int Nn = in_sizes[0] / 128;   // 50000
    const int E  = in_sizes[1] / 2;     // 800000
    const int ET = E + Nn;
    const int* srcp = ei;
    const int* dstp = ei + E;

    float* ws  = (float*)d_ws;
    float* X0  = ws;                          // [N,256]
    float* XP  = X0  + (size_t)Nn * 256;      // [N,256]
    float* G   = XP  + (size_t)Nn * 256;      // [N,256]
    float* R   = G   + (size_t)Nn * 256;      // [N,256]
    float* HIN = R   + (size_t)Nn * 256;      // [N,128]
    float* AS  = HIN + (size_t)Nn * 128;      // [N,8]
    float* AD  = AS  + (size_t)Nn * 8;        // [N,8]
    float* DEN = AD  + (size_t)Nn * 8;        // [N,8]

    dim3 blk(256);
    int rb = (Nn + 63) / 64;  // 782

    // stage 0: X0 = x @ W_tr + b_tr    [N,128] -> [N,256]
    gemm_k<<<dim3(4, rb), blk, 0, stream>>>(x, 128, nullptr, 0, W_tr, b_tr, X0, Nn, 256, 0);

    // ================= layer 1 (D=256, H=8, C=32, h_in = X0) =================
    gemm_k<<<dim3(4, rb), blk, 0, stream>>>(X0, 256, nullptr, 0, W1, nullptr, XP, Nn, 256, 0);
    alpha_k<<<(Nn * 8 + 255) / 256, blk, 0, stream>>>(XP, as1, ad1, AS, AD, Nn, 8, 32);
    hipMemsetAsync(DEN, 0, (size_t)Nn * 8 * 4, stream);
    hipMemsetAsync(G,   0, (size_t)Nn * 256 * 4, stream);
    edge_denom<<<(ET + 255) / 256, blk, 0, stream>>>(srcp, dstp, E, Nn, 8, AS, AD, DEN);
    launch_edge_agg(srcp, dstp, E, Nn, 8, 32, XP, AS, AD, DEN, G, stream);
    bias_act<<<(int)(((long)Nn * 256 + 255) / 256), blk, 0, stream>>>(G, b1, (long)Nn * 256, 256, 1);
    gemm_k<<<dim3(4, rb), blk, 0, stream>>>(G, 256, X0, 256, Wr1, br1, R, Nn, 256, 1);
    gru_fused_k<<<dim3(4, rb), blk, 0, stream>>>(G, X0, R, 256, Wz1, bz1, Wh1, bh1, XP, Nn);

    float* cx    = XP;   // current x [N,256]
    float* spare = X0;   // free

    // ================= layer 2 (H=4, C=32, out 128) =================
    gemm_k<<<dim3(2, rb), blk, 0, stream>>>(cx, 256, nullptr, 0, Wp2, bp2, HIN, Nn, 128, 0);
    gemm_k<<<dim3(2, rb), blk, 0, stream>>>(cx, 256, nullptr, 0, W2, nullptr, spare, Nn, 128, 0);
    alpha_k<<<(Nn * 4 + 255) / 256, blk, 0, stream>>>(spare, as2, ad2, AS, AD, Nn, 4, 32);
    hipMemsetAsync(DEN, 0, (size_t)Nn * 4 * 4, stream);
    hipMemsetAsync(G,   0, (size_t)Nn * 128 * 4, stream);
    edge_denom<<<(ET + 255) / 256, blk, 0, stream>>>(srcp, dstp, E, Nn, 4, AS, AD, DEN);
    launch_edge_agg(srcp, dstp, E, Nn, 4, 32, spare, AS, AD, DEN, G, stream);
    bias_act<<<(int)(((long)Nn * 128 + 255) / 256), blk, 0, stream>>>(G, b2, (long)Nn * 128, 128, 1);
    gemm_k<<<dim3(2, rb), blk, 0, stream>>>(G, 128, HIN, 128, Wr2, br2, R, Nn, 128, 1);
    gru_fused_k<<<dim3(2, rb), blk, 0, stream>>>(G, HIN, R, 128, Wz2, bz2, Wh2, bh2, cx, Nn);
    // cx now holds x [N,128]; spare free

    // ================= layer 3 (H=1, C=64, out 64, no ELU) =================
    gemm_k<<<dim3(1, rb), blk, 0, stream>>>(cx, 128, nullptr, 0, Wp3, bp3, HIN, Nn, 64, 0);
    gemm_k<<<dim3(1, rb), blk, 0, stream>>>(cx, 128, nullptr, 0, W3, nullptr, spare, Nn, 64, 0);
    alpha_k<<<(Nn + 255) / 256, blk, 0, stream>>>(spare, as3, ad3, AS, AD, Nn, 1, 64);
    hipMemsetAsync(DEN, 0, (size_t)Nn * 4, stream);
    hipMemsetAsync(G,   0, (size_t)Nn * 64 * 4, stream);
    edge_denom<<<(ET + 255) / 256, blk, 0, stream>>>(srcp, dstp, E, Nn, 1, AS, AD, DEN);
    launch_edge_agg(srcp, dstp, E, Nn, 1, 64, spare, AS, AD, DEN, G, stream);
    bias_act<<<(int)(((long)Nn * 64 + 255) / 256), blk, 0, stream>>>(G, b3, (long)Nn * 64, 64, 0);
    gemm_k<<<dim3(1, rb), blk, 0, stream>>>(G, 64, HIN, 64, Wr3, br3, R, Nn, 64, 1);
    gru_fused_k<<<dim3(1, rb), blk, 0, stream>>>(G, HIN, R, 64, Wz3, bz3, Wh3, bh3, (float*)d_out, Nn);
}

// Round 2
// 2025.602 us; speedup vs baseline: 3.6082x; 3.6082x over previous
//
#include <hip/hip_runtime.h>

#define NEG_SLOPE 0.2f

// ---------------- generic tiled SGEMM: C = act(concat(U,V) @ W + bias) ----------------
__global__ __launch_bounds__(256) void gemm_k(
    const float* __restrict__ U, int K1,
    const float* __restrict__ V, int K2,
    const float* __restrict__ W, const float* __restrict__ bias,
    float* __restrict__ Cout, int rows, int Mo, int act)
{
    __shared__ float As[16][65];
    __shared__ float Bs[16][64];
    const int tid = threadIdx.x;
    const int row0 = blockIdx.y * 64;
    const int col0 = blockIdx.x * 64;
    const int tx = tid & 15, ty = tid >> 4;
    const int K = K1 + K2;
    float acc[4][4] = {};
    for (int k0 = 0; k0 < K; k0 += 16) {
#pragma unroll
        for (int i = 0; i < 4; ++i) {
            int idx = tid + i * 256;
            int rl = idx >> 4, kl = idx & 15;
            int r = row0 + rl, k = k0 + kl;
            float v = 0.f;
            if (r < rows) {
                if (k < K1) v = U[(long)r * K1 + k];
                else        v = V[(long)r * K2 + (k - K1)];
            }
            As[kl][rl] = v;
        }
#pragma unroll
        for (int i = 0; i < 4; ++i) {
            int idx = tid + i * 256;
            int kl = idx >> 6, jl = idx & 63;
            Bs[kl][jl] = W[(long)(k0 + kl) * Mo + (col0 + jl)];
        }
        __syncthreads();
#pragma unroll
        for (int k = 0; k < 16; ++k) {
            float a[4], b[4];
#pragma unroll
            for (int i = 0; i < 4; ++i) a[i] = As[k][ty * 4 + i];
#pragma unroll
            for (int j = 0; j < 4; ++j) b[j] = Bs[k][tx * 4 + j];
#pragma unroll
            for (int i = 0; i < 4; ++i)
#pragma unroll
                for (int j = 0; j < 4; ++j)
                    acc[i][j] += a[i] * b[j];
        }
        __syncthreads();
    }
#pragma unroll
    for (int i = 0; i < 4; ++i) {
        int r = row0 + ty * 4 + i;
        if (r >= rows) continue;
#pragma unroll
        for (int j = 0; j < 4; ++j) {
            int c = col0 + tx * 4 + j;
            float v = acc[i][j] + (bias ? bias[c] : 0.f);
            if (act == 1) v = 1.f / (1.f + __expf(-v));
            Cout[(long)r * Mo + c] = v;
        }
    }
}

// ---------------- fused GRU: z-GEMM + hhat-GEMM + output elementwise ----------------
__global__ __launch_bounds__(256) void gru_fused_k(
    const float* __restrict__ Gp, const float* __restrict__ Hin,
    const float* __restrict__ Rp, int D,
    const float* __restrict__ Wz, const float* __restrict__ bz,
    const float* __restrict__ Wh, const float* __restrict__ bh,
    float* __restrict__ Out, int rows)
{
    __shared__ float Az[16][65];
    __shared__ float Ah[16][65];
    __shared__ float Bz[16][64];
    __shared__ float Bh[16][64];
    const int tid = threadIdx.x;
    const int row0 = blockIdx.y * 64;
    const int col0 = blockIdx.x * 64;
    const int tx = tid & 15, ty = tid >> 4;
    const int K = 2 * D;
    float accz[4][4] = {}, acch[4][4] = {};
    for (int k0 = 0; k0 < K; k0 += 16) {
#pragma unroll
        for (int i = 0; i < 4; ++i) {
            int idx = tid + i * 256;
            int rl = idx >> 4, kl = idx & 15;
            int r = row0 + rl, k = k0 + kl;
            float vz = 0.f, vh = 0.f;
            if (r < rows) {
                if (k < D) { vz = Gp[(long)r * D + k]; vh = vz; }
                else {
                    int k2 = k - D;
                    float hv = Hin[(long)r * D + k2];
                    vz = hv; vh = hv * Rp[(long)r * D + k2];
                }
            }
            Az[kl][rl] = vz; Ah[kl][rl] = vh;
        }
#pragma unroll
        for (int i = 0; i < 4; ++i) {
            int idx = tid + i * 256;
            int kl = idx >> 6, jl = idx & 63;
            Bz[kl][jl] = Wz[(long)(k0 + kl) * D + (col0 + jl)];
            Bh[kl][jl] = Wh[(long)(k0 + kl) * D + (col0 + jl)];
        }
        __syncthreads();
#pragma unroll
        for (int k = 0; k < 16; ++k) {
            float az[4], ah[4], bzv[4], bhv[4];
#pragma unroll
            for (int i = 0; i < 4; ++i) { az[i] = Az[k][ty * 4 + i]; ah[i] = Ah[k][ty * 4 + i]; }
#pragma unroll
            for (int j = 0; j < 4; ++j) { bzv[j] = Bz[k][tx * 4 + j]; bhv[j] = Bh[k][tx * 4 + j]; }
#pragma unroll
            for (int i = 0; i < 4; ++i)
#pragma unroll
                for (int j = 0; j < 4; ++j) {
                    accz[i][j] += az[i] * bzv[j];
                    acch[i][j] += ah[i] * bhv[j];
                }
        }
        __syncthreads();
    }
#pragma unroll
    for (int i = 0; i < 4; ++i) {
        int r = row0 + ty * 4 + i;
        if (r >= rows) continue;
#pragma unroll
        for (int j = 0; j < 4; ++j) {
            int c = col0 + tx * 4 + j;
            float z = 1.f / (1.f + __expf(-(accz[i][j] + bz[c])));
            float hh = tanhf(acch[i][j] + bh[c]);
            float hv = Hin[(long)r * D + c];
            Out[(long)r * D + c] = (1.f - z) * hv + z * hh;
        }
    }
}

// ---------------- alpha_s / alpha_d per (node, head) ----------------
__global__ void alpha_k(const float* __restrict__ XP,
                        const float* __restrict__ a_s, const float* __restrict__ a_d,
                        float* __restrict__ AS, float* __restrict__ AD,
                        int Nn, int H, int C)
{
    int i = blockIdx.x * blockDim.x + threadIdx.x;
    if (i >= Nn * H) return;
    int n = i / H, h = i % H;
    const float* xp = &XP[(long)n * H * C + (long)h * C];
    float ss = 0.f, sd = 0.f;
    for (int c = 0; c < C; ++c) {
        float v = xp[c];
        ss += v * a_s[h * C + c];
        sd += v * a_d[h * C + c];
    }
    AS[i] = ss; AD[i] = sd;
}

// ---------------- CSR build: count incoming edges per dst ----------------
__global__ void count_k(const int* __restrict__ dst, int E, int* __restrict__ cnt)
{
    int e = blockIdx.x * blockDim.x + threadIdx.x;
    if (e < E) atomicAdd(&cnt[dst[e]], 1);
}

// single-block exclusive scan over cnt[Nn] -> off[Nn+1]
__global__ __launch_bounds__(1024) void scan_k(const int* __restrict__ cnt, int Nn,
                                               int* __restrict__ off)
{
    __shared__ int part[1024];
    int tid = threadIdx.x;
    int chunk = (Nn + 1023) / 1024;
    int b = tid * chunk;
    int e = b + chunk; if (e > Nn) e = Nn; if (b > Nn) b = Nn;
    int s = 0;
    for (int i = b; i < e; ++i) s += cnt[i];
    part[tid] = s;
    __syncthreads();
    for (int d = 1; d < 1024; d <<= 1) {
        int v = (tid >= d) ? part[tid - d] : 0;
        __syncthreads();
        part[tid] += v;
        __syncthreads();
    }
    int run = tid ? part[tid - 1] : 0;
    for (int i = b; i < e; ++i) { off[i] = run; run += cnt[i]; }
    if (tid == 1023) off[Nn] = part[1023];
}

__global__ void scatter_k(const int* __restrict__ src, const int* __restrict__ dst, int E,
                          const int* __restrict__ off, int* __restrict__ cur,
                          int* __restrict__ csr_src)
{
    int e = blockIdx.x * blockDim.x + threadIdx.x;
    if (e < E) {
        int d = dst[e];
        int p = atomicAdd(&cur[d], 1);
        csr_src[off[d] + p] = src[e];
    }
}

// ---------------- fused GAT gather: softmax-weighted aggregation + bias + ELU --------
// One node per 64/npw lanes; lane owns 4 contiguous features (float4).
// out[n,:] = (wself*xp[n,:] + sum_e w_e * xp[src_e,:]) / (wself + sum w_e) + bias, ELU opt.
__global__ void gat_gather(const int* __restrict__ off, const int* __restrict__ csr_src,
                           const float* __restrict__ XP,
                           const float* __restrict__ AS, const float* __restrict__ AD,
                           const float* __restrict__ bias,
                           float* __restrict__ Gout, int Nn, int H, int C, int do_elu)
{
    const int D = H * C;
    const int lpn = D >> 2;        // lanes per node
    const int npw = 64 / lpn;      // nodes per wave
    int lane = threadIdx.x & 63;
    long wave = ((long)blockIdx.x * blockDim.x + threadIdx.x) >> 6;
    int sub = lane / lpn;
    int cl = lane % lpn;
    long n = wave * npw + sub;
    if (n >= Nn) return;
    int j = cl * 4;
    int h = j / C;
    float ad = AD[n * H + h];
    // self-loop
    float v = AS[n * H + h] + ad;
    v = v > 0.f ? v : NEG_SLOPE * v;
    float w = __expf(v);
    float den = w;
    float4 xv = *(const float4*)&XP[(long)n * D + j];
    float4 acc;
    acc.x = w * xv.x; acc.y = w * xv.y; acc.z = w * xv.z; acc.w = w * xv.w;
    int b0 = off[n], b1 = off[n + 1];
    for (int i = b0; i < b1; ++i) {
        int s = csr_src[i];
        v = AS[s * H + h] + ad;
        v = v > 0.f ? v : NEG_SLOPE * v;
        w = __expf(v);
        den += w;
        xv = *(const float4*)&XP[(long)s * D + j];
        acc.x += w * xv.x; acc.y += w * xv.y; acc.z += w * xv.z; acc.w += w * xv.w;
    }
    float inv = 1.f / (den + 1e-16f);
    float4 bv = *(const float4*)&bias[j];
    float o0 = acc.x * inv + bv.x;
    float o1 = acc.y * inv + bv.y;
    float o2 = acc.z * inv + bv.z;
    float o3 = acc.w * inv + bv.w;
    if (do_elu) {
        o0 = o0 > 0.f ? o0 : expm1f(o0);
        o1 = o1 > 0.f ? o1 : expm1f(o1);
        o2 = o2 > 0.f ? o2 : expm1f(o2);
        o3 = o3 > 0.f ? o3 : expm1f(o3);
    }
    float4* op = (float4*)&Gout[(long)n * D + j];
    float4 ov; ov.x = o0; ov.y = o1; ov.z = o2; ov.w = o3;
    *op = ov;
}

static inline void launch_gather(const int* off, const int* csr, const float* XP,
                                 const float* AS, const float* AD, const float* bias,
                                 float* Gout, int Nn, int H, int C, int do_elu,
                                 hipStream_t stream)
{
    int D = H * C;
    int lpn = D >> 2;
    int npw = 64 / lpn;
    long waves = (Nn + npw - 1) / npw;
    long thr = waves * 64;
    int blocks = (int)((thr + 255) / 256);
    gat_gather<<<blocks, 256, 0, stream>>>(off, csr, XP, AS, AD, bias, Gout, Nn, H, C, do_elu);
}

extern "C" void kernel_launch(void* const* d_in, const int* in_sizes, int n_in,
                              void* d_out, int out_size, void* d_ws, size_t ws_size,
                              hipStream_t stream)
{
    const float* x    = (const float*)d_in[0];
    const int*   ei   = (const int*)  d_in[1];
    const float* W_tr = (const float*)d_in[2];
    const float* b_tr = (const float*)d_in[3];
    const float* W1   = (const float*)d_in[4];
    const float* as1  = (const float*)d_in[5];
    const float* ad1  = (const float*)d_in[6];
    const float* b1   = (const float*)d_in[7];
    const float* Wr1  = (const float*)d_in[8];
    const float* br1  = (const float*)d_in[9];
    const float* Wz1  = (const float*)d_in[10];
    const float* bz1  = (const float*)d_in[11];
    const float* Wh1  = (const float*)d_in[12];
    const float* bh1  = (const float*)d_in[13];
    const float* Wp2  = (const float*)d_in[14];
    const float* bp2  = (const float*)d_in[15];
    const float* W2   = (const float*)d_in[16];
    const float* as2  = (const float*)d_in[17];
    const float* ad2  = (const float*)d_in[18];
    const float* b2   = (const float*)d_in[19];
    const float* Wr2  = (const float*)d_in[20];
    const float* br2  = (const float*)d_in[21];
    const float* Wz2  = (const float*)d_in[22];
    const float* bz2  = (const float*)d_in[23];
    const float* Wh2  = (const float*)d_in[24];
    const float* bh2  = (const float*)d_in[25];
    const float* Wp3  = (const float*)d_in[26];
    const float* bp3  = (const float*)d_in[27];
    const float* W3   = (const float*)d_in[28];
    const float* as3  = (const float*)d_in[29];
    const float* ad3  = (const float*)d_in[30];
    const float* b3   = (const float*)d_in[31];
    const float* Wr3  = (const float*)d_in[32];
    const float* br3  = (const float*)d_in[33];
    const float* Wz3  = (const float*)d_in[34];
    const float* bz3  = (const float*)d_in[35];
    const float* Wh3  = (const float*)d_in[36];
    const float* bh3  = (const float*)d_in[37];

    const int Nn = in_sizes[0] / 128;   // 50000
    const int E  = in_sizes[1] / 2;     // 800000
    const int* srcp = ei;
    const int* dstp = ei + E;

    float* ws  = (float*)d_ws;
    float* X0  = ws;                          // [N,256]
    float* XP  = X0  + (size_t)Nn * 256;      // [N,256]
    float* G   = XP  + (size_t)Nn * 256;      // [N,256]
    float* R   = G   + (size_t)Nn * 256;      // [N,256]
    float* HIN = R   + (size_t)Nn * 256;      // [N,128]
    float* AS  = HIN + (size_t)Nn * 128;      // [N,8]
    float* AD  = AS  + (size_t)Nn * 8;        // [N,8]
    int*   ioff = (int*)(AD + (size_t)Nn * 8);// [N+1]
    int*   cnt  = ioff + (Nn + 1);            // [N]
    int*   cur  = cnt + Nn;                   // [N]
    int*   csr  = cur + Nn;                   // [E]

    dim3 blk(256);
    int rb = (Nn + 63) / 64;  // 782

    // ---------- CSR build (once; shared by all 3 layers) ----------
    hipMemsetAsync(cnt, 0, (size_t)Nn * 4, stream);
    hipMemsetAsync(cur, 0, (size_t)Nn * 4, stream);
    count_k<<<(E + 255) / 256, blk, 0, stream>>>(dstp, E, cnt);
    scan_k<<<1, 1024, 0, stream>>>(cnt, Nn, ioff);
    scatter_k<<<(E + 255) / 256, blk, 0, stream>>>(srcp, dstp, E, ioff, cur, csr);

    // stage 0: X0 = x @ W_tr + b_tr    [N,128] -> [N,256]
    gemm_k<<<dim3(4, rb), blk, 0, stream>>>(x, 128, nullptr, 0, W_tr, b_tr, X0, Nn, 256, 0);

    // ================= layer 1 (D=256, H=8, C=32, h_in = X0) =================
    gemm_k<<<dim3(4, rb), blk, 0, stream>>>(X0, 256, nullptr, 0, W1, nullptr, XP, Nn, 256, 0);
    alpha_k<<<(Nn * 8 + 255) / 256, blk, 0, stream>>>(XP, as1, ad1, AS, AD, Nn, 8, 32);
    launch_gather(ioff, csr, XP, AS, AD, b1, G, Nn, 8, 32, 1, stream);
    gemm_k<<<dim3(4, rb), blk, 0, stream>>>(G, 256, X0, 256, Wr1, br1, R, Nn, 256, 1);
    gru_fused_k<<<dim3(4, rb), blk, 0, stream>>>(G, X0, R, 256, Wz1, bz1, Wh1, bh1, XP, Nn);

    float* cx    = XP;   // current x [N,256]
    float* spare = X0;   // free

    // ================= layer 2 (H=4, C=32, out 128) =================
    gemm_k<<<dim3(2, rb), blk, 0, stream>>>(cx, 256, nullptr, 0, Wp2, bp2, HIN, Nn, 128, 0);
    gemm_k<<<dim3(2, rb), blk, 0, stream>>>(cx, 256, nullptr, 0, W2, nullptr, spare, Nn, 128, 0);
    alpha_k<<<(Nn * 4 + 255) / 256, blk, 0, stream>>>(spare, as2, ad2, AS, AD, Nn, 4, 32);
    launch_gather(ioff, csr, spare, AS, AD, b2, G, Nn, 4, 32, 1, stream);
    gemm_k<<<dim3(2, rb), blk, 0, stream>>>(G, 128, HIN, 128, Wr2, br2, R, Nn, 128, 1);
    gru_fused_k<<<dim3(2, rb), blk, 0, stream>>>(G, HIN, R, 128, Wz2, bz2, Wh2, bh2, cx, Nn);
    // cx now holds x [N,128]; spare free

    // ================= layer 3 (H=1, C=64, out 64, no ELU) =================
    gemm_k<<<dim3(1, rb), blk, 0, stream>>>(cx, 128, nullptr, 0, Wp3, bp3, HIN, Nn, 64, 0);
    gemm_k<<<dim3(1, rb), blk, 0, stream>>>(cx, 128, nullptr, 0, W3, nullptr, spare, Nn, 64, 0);
    alpha_k<<<(Nn + 255) / 256, blk, 0, stream>>>(spare, as3, ad3, AS, AD, Nn, 1, 64);
    launch_gather(ioff, csr, spare, AS, AD, b3, G, Nn, 1, 64, 0, stream);
    gemm_k<<<dim3(1, rb), blk, 0, stream>>>(G, 64, HIN, 64, Wr3, br3, R, Nn, 64, 1);
    gru_fused_k<<<dim3(1, rb), blk, 0, stream>>>(G, HIN, R, 64, Wz3, bz3, Wh3, bh3, (float*)d_out, Nn);
}

// Round 3
// 1059.186 us; speedup vs baseline: 6.9004x; 1.9124x over previous
//
#include <hip/hip_runtime.h>

#define NEG_SLOPE 0.2f

typedef __attribute__((ext_vector_type(8))) short short8;
typedef __attribute__((ext_vector_type(4))) float f32x4;

__device__ __forceinline__ unsigned short f2bf(float f) {
    unsigned int u = __float_as_uint(f);
    u += 0x7fff + ((u >> 16) & 1);     // round-to-nearest-even
    return (unsigned short)(u >> 16);
}

// ================= MFMA GEMM: C = act(concat(U,V) @ W + bias) =================
// BM=128, BN=64, BK=32. 256 thr = 4 waves, wave-tile 32x64 (2x4 frags).
// LDS subtile layout [kgroup][m][8] -> fragment = one aligned ds_read_b128.
__global__ __launch_bounds__(256) void gemm_mfma(
    const float* __restrict__ U, int K1,
    const float* __restrict__ V, int K2,
    const float* __restrict__ W, const float* __restrict__ bias,
    float* __restrict__ Cout, int rows, int Mo, int act)
{
    __shared__ __align__(16) unsigned short As[4][128][8];
    __shared__ __align__(16) unsigned short Bs[4][64][8];
    const int tid = threadIdx.x;
    const int row0 = blockIdx.y * 128;
    const int col0 = blockIdx.x * 64;
    const int K = K1 + K2;
    const int l = tid & 63, w = tid >> 6;
    const int lm = l & 15, lg = l >> 4;
    f32x4 acc[2][4] = {};

    const int am = tid >> 1;      // A-staging row 0..127
    const int ahf = tid & 1;      // which 16-wide k half
    const int arow = row0 + am;
    const int bn = tid & 63, bg = tid >> 6;   // B-staging

    for (int k0 = 0; k0 < K; k0 += 32) {
        // ---- stage A: 128x32 fp32 -> bf16 ----
        {
            int kb = k0 + ahf * 16;
            unsigned short t16[16];
            if (arow < rows) {
                const float* sp = (kb < K1) ? (U + (long)arow * K1 + kb)
                                            : (V + (long)arow * K2 + (kb - K1));
#pragma unroll
                for (int q = 0; q < 4; ++q) {
                    float4 f = *(const float4*)(sp + q * 4);
                    t16[q*4+0] = f2bf(f.x); t16[q*4+1] = f2bf(f.y);
                    t16[q*4+2] = f2bf(f.z); t16[q*4+3] = f2bf(f.w);
                }
            } else {
#pragma unroll
                for (int q = 0; q < 16; ++q) t16[q] = 0;
            }
#pragma unroll
            for (int q = 0; q < 4; ++q) {
                int kl = ahf * 16 + q * 4;
                ushort4 v4; v4.x = t16[q*4+0]; v4.y = t16[q*4+1];
                v4.z = t16[q*4+2]; v4.w = t16[q*4+3];
                *(ushort4*)&As[kl >> 3][am][kl & 7] = v4;
            }
        }
        // ---- stage B: 32x64, coalesced per j-row ----
        {
            const float* wp = W + (long)(k0 + bg * 8) * Mo + col0 + bn;
            unsigned short t8[8];
#pragma unroll
            for (int j = 0; j < 8; ++j) t8[j] = f2bf(wp[(long)j * Mo]);
            ushort4 lo, hi;
            lo.x=t8[0]; lo.y=t8[1]; lo.z=t8[2]; lo.w=t8[3];
            hi.x=t8[4]; hi.y=t8[5]; hi.z=t8[6]; hi.w=t8[7];
            *(ushort4*)&Bs[bg][bn][0] = lo;
            *(ushort4*)&Bs[bg][bn][4] = hi;
        }
        __syncthreads();
        short8 a[2], b[4];
#pragma unroll
        for (int mi = 0; mi < 2; ++mi)
            a[mi] = *(const short8*)&As[lg][w * 32 + mi * 16 + lm][0];
#pragma unroll
        for (int ni = 0; ni < 4; ++ni)
            b[ni] = *(const short8*)&Bs[lg][ni * 16 + lm][0];
#pragma unroll
        for (int mi = 0; mi < 2; ++mi)
#pragma unroll
            for (int ni = 0; ni < 4; ++ni)
                acc[mi][ni] = __builtin_amdgcn_mfma_f32_16x16x32_bf16(a[mi], b[ni], acc[mi][ni], 0, 0, 0);
        __syncthreads();
    }
#pragma unroll
    for (int mi = 0; mi < 2; ++mi) {
        int rbase = row0 + w * 32 + mi * 16 + lg * 4;
#pragma unroll
        for (int r = 0; r < 4; ++r) {
            int row = rbase + r;
            if (row >= rows) continue;
#pragma unroll
            for (int ni = 0; ni < 4; ++ni) {
                int col = col0 + ni * 16 + lm;
                float v = acc[mi][ni][r] + (bias ? bias[col] : 0.f);
                if (act == 1) v = 1.f / (1.f + __expf(-v));
                Cout[(long)row * Mo + col] = v;
            }
        }
    }
}

// ================= MFMA fused GRU: z-GEMM + hhat-GEMM + elementwise ==========
__global__ __launch_bounds__(256) void gru_mfma(
    const float* __restrict__ Gp, const float* __restrict__ Hin,
    const float* __restrict__ Rp, int D,
    const float* __restrict__ Wz, const float* __restrict__ bz,
    const float* __restrict__ Wh, const float* __restrict__ bh,
    float* __restrict__ Out, int rows)
{
    __shared__ __align__(16) unsigned short Asz[4][128][8];
    __shared__ __align__(16) unsigned short Ash[4][128][8];
    __shared__ __align__(16) unsigned short Bsz[4][64][8];
    __shared__ __align__(16) unsigned short Bsh[4][64][8];
    const int tid = threadIdx.x;
    const int row0 = blockIdx.y * 128;
    const int col0 = blockIdx.x * 64;
    const int K = 2 * D;
    const int l = tid & 63, w = tid >> 6;
    const int lm = l & 15, lg = l >> 4;
    f32x4 accz[2][4] = {}, acch[2][4] = {};

    const int am = tid >> 1;
    const int ahf = tid & 1;
    const int arow = row0 + am;
    const int bn = tid & 63, bg = tid >> 6;

    for (int k0 = 0; k0 < K; k0 += 32) {
        // ---- stage A (z and h variants) ----
        {
            int kb = k0 + ahf * 16;
            unsigned short tz[16], th[16];
            if (arow < rows) {
                if (kb < D) {
                    const float* sp = Gp + (long)arow * D + kb;
#pragma unroll
                    for (int q = 0; q < 4; ++q) {
                        float4 f = *(const float4*)(sp + q * 4);
                        unsigned short b0 = f2bf(f.x), b1 = f2bf(f.y), b2 = f2bf(f.z), b3 = f2bf(f.w);
                        tz[q*4+0]=b0; tz[q*4+1]=b1; tz[q*4+2]=b2; tz[q*4+3]=b3;
                        th[q*4+0]=b0; th[q*4+1]=b1; th[q*4+2]=b2; th[q*4+3]=b3;
                    }
                } else {
                    const float* hp = Hin + (long)arow * D + (kb - D);
                    const float* rp = Rp  + (long)arow * D + (kb - D);
#pragma unroll
                    for (int q = 0; q < 4; ++q) {
                        float4 f = *(const float4*)(hp + q * 4);
                        float4 r = *(const float4*)(rp + q * 4);
                        tz[q*4+0]=f2bf(f.x); tz[q*4+1]=f2bf(f.y); tz[q*4+2]=f2bf(f.z); tz[q*4+3]=f2bf(f.w);
                        th[q*4+0]=f2bf(f.x*r.x); th[q*4+1]=f2bf(f.y*r.y);
                        th[q*4+2]=f2bf(f.z*r.z); th[q*4+3]=f2bf(f.w*r.w);
                    }
                }
            } else {
#pragma unroll
                for (int q = 0; q < 16; ++q) { tz[q] = 0; th[q] = 0; }
            }
#pragma unroll
            for (int q = 0; q < 4; ++q) {
                int kl = ahf * 16 + q * 4;
                ushort4 vz, vh;
                vz.x=tz[q*4+0]; vz.y=tz[q*4+1]; vz.z=tz[q*4+2]; vz.w=tz[q*4+3];
                vh.x=th[q*4+0]; vh.y=th[q*4+1]; vh.z=th[q*4+2]; vh.w=th[q*4+3];
                *(ushort4*)&Asz[kl >> 3][am][kl & 7] = vz;
                *(ushort4*)&Ash[kl >> 3][am][kl & 7] = vh;
            }
        }
        // ---- stage B (Wz and Wh) ----
        {
            const float* wpz = Wz + (long)(k0 + bg * 8) * D + col0 + bn;
            const float* wph = Wh + (long)(k0 + bg * 8) * D + col0 + bn;
            unsigned short tz[8], th[8];
#pragma unroll
            for (int j = 0; j < 8; ++j) { tz[j] = f2bf(wpz[(long)j * D]); th[j] = f2bf(wph[(long)j * D]); }
            ushort4 a0, a1, b0, b1;
            a0.x=tz[0]; a0.y=tz[1]; a0.z=tz[2]; a0.w=tz[3];
            a1.x=tz[4]; a1.y=tz[5]; a1.z=tz[6]; a1.w=tz[7];
            b0.x=th[0]; b0.y=th[1]; b0.z=th[2]; b0.w=th[3];
            b1.x=th[4]; b1.y=th[5]; b1.z=th[6]; b1.w=th[7];
            *(ushort4*)&Bsz[bg][bn][0] = a0;
            *(ushort4*)&Bsz[bg][bn][4] = a1;
            *(ushort4*)&Bsh[bg][bn][0] = b0;
            *(ushort4*)&Bsh[bg][bn][4] = b1;
        }
        __syncthreads();
        short8 az[2], ah[2], bzf[4], bhf[4];
#pragma unroll
        for (int mi = 0; mi < 2; ++mi) {
            az[mi] = *(const short8*)&Asz[lg][w * 32 + mi * 16 + lm][0];
            ah[mi] = *(const short8*)&Ash[lg][w * 32 + mi * 16 + lm][0];
        }
#pragma unroll
        for (int ni = 0; ni < 4; ++ni) {
            bzf[ni] = *(const short8*)&Bsz[lg][ni * 16 + lm][0];
            bhf[ni] = *(const short8*)&Bsh[lg][ni * 16 + lm][0];
        }
#pragma unroll
        for (int mi = 0; mi < 2; ++mi)
#pragma unroll
            for (int ni = 0; ni < 4; ++ni) {
                accz[mi][ni] = __builtin_amdgcn_mfma_f32_16x16x32_bf16(az[mi], bzf[ni], accz[mi][ni], 0, 0, 0);
                acch[mi][ni] = __builtin_amdgcn_mfma_f32_16x16x32_bf16(ah[mi], bhf[ni], acch[mi][ni], 0, 0, 0);
            }
        __syncthreads();
    }
#pragma unroll
    for (int mi = 0; mi < 2; ++mi) {
        int rbase = row0 + w * 32 + mi * 16 + lg * 4;
#pragma unroll
        for (int r = 0; r < 4; ++r) {
            int row = rbase + r;
            if (row >= rows) continue;
#pragma unroll
            for (int ni = 0; ni < 4; ++ni) {
                int col = col0 + ni * 16 + lm;
                float z  = 1.f / (1.f + __expf(-(accz[mi][ni][r] + bz[col])));
                float hh = tanhf(acch[mi][ni][r] + bh[col]);
                float hv = Hin[(long)row * D + col];
                Out[(long)row * D + col] = (1.f - z) * hv + z * hh;
            }
        }
    }
}

// ================= fp32 tiled SGEMM (layer-3 precision buffer) =================
__global__ __launch_bounds__(256) void gemm_k(
    const float* __restrict__ U, int K1,
    const float* __restrict__ V, int K2,
    const float* __restrict__ W, const float* __restrict__ bias,
    float* __restrict__ Cout, int rows, int Mo, int act)
{
    __shared__ float As[16][65];
    __shared__ float Bs[16][64];
    const int tid = threadIdx.x;
    const int row0 = blockIdx.y * 64;
    const int col0 = blockIdx.x * 64;
    const int tx = tid & 15, ty = tid >> 4;
    const int K = K1 + K2;
    float acc[4][4] = {};
    for (int k0 = 0; k0 < K; k0 += 16) {
#pragma unroll
        for (int i = 0; i < 4; ++i) {
            int idx = tid + i * 256;
            int rl = idx >> 4, kl = idx & 15;
            int r = row0 + rl, k = k0 + kl;
            float v = 0.f;
            if (r < rows) {
                if (k < K1) v = U[(long)r * K1 + k];
                else        v = V[(long)r * K2 + (k - K1)];
            }
            As[kl][rl] = v;
        }
#pragma unroll
        for (int i = 0; i < 4; ++i) {
            int idx = tid + i * 256;
            int kl = idx >> 6, jl = idx & 63;
            Bs[kl][jl] = W[(long)(k0 + kl) * Mo + (col0 + jl)];
        }
        __syncthreads();
#pragma unroll
        for (int k = 0; k < 16; ++k) {
            float a[4], b[4];
#pragma unroll
            for (int i = 0; i < 4; ++i) a[i] = As[k][ty * 4 + i];
#pragma unroll
            for (int j = 0; j < 4; ++j) b[j] = Bs[k][tx * 4 + j];
#pragma unroll
            for (int i = 0; i < 4; ++i)
#pragma unroll
                for (int j = 0; j < 4; ++j)
                    acc[i][j] += a[i] * b[j];
        }
        __syncthreads();
    }
#pragma unroll
    for (int i = 0; i < 4; ++i) {
        int r = row0 + ty * 4 + i;
        if (r >= rows) continue;
#pragma unroll
        for (int j = 0; j < 4; ++j) {
            int c = col0 + tx * 4 + j;
            float v = acc[i][j] + (bias ? bias[c] : 0.f);
            if (act == 1) v = 1.f / (1.f + __expf(-v));
            Cout[(long)r * Mo + c] = v;
        }
    }
}

// ---------------- fp32 fused GRU (layer 3) ----------------
__global__ __launch_bounds__(256) void gru_fused_k(
    const float* __restrict__ Gp, const float* __restrict__ Hin,
    const float* __restrict__ Rp, int D,
    const float* __restrict__ Wz, const float* __restrict__ bz,
    const float* __restrict__ Wh, const float* __restrict__ bh,
    float* __restrict__ Out, int rows)
{
    __shared__ float Az[16][65];
    __shared__ float Ah[16][65];
    __shared__ float Bz[16][64];
    __shared__ float Bh[16][64];
    const int tid = threadIdx.x;
    const int row0 = blockIdx.y * 64;
    const int col0 = blockIdx.x * 64;
    const int tx = tid & 15, ty = tid >> 4;
    const int K = 2 * D;
    float accz[4][4] = {}, acch[4][4] = {};
    for (int k0 = 0; k0 < K; k0 += 16) {
#pragma unroll
        for (int i = 0; i < 4; ++i) {
            int idx = tid + i * 256;
            int rl = idx >> 4, kl = idx & 15;
            int r = row0 + rl, k = k0 + kl;
            float vz = 0.f, vh = 0.f;
            if (r < rows) {
                if (k < D) { vz = Gp[(long)r * D + k]; vh = vz; }
                else {
                    int k2 = k - D;
                    float hv = Hin[(long)r * D + k2];
                    vz = hv; vh = hv * Rp[(long)r * D + k2];
                }
            }
            Az[kl][rl] = vz; Ah[kl][rl] = vh;
        }
#pragma unroll
        for (int i = 0; i < 4; ++i) {
            int idx = tid + i * 256;
            int kl = idx >> 6, jl = idx & 63;
            Bz[kl][jl] = Wz[(long)(k0 + kl) * D + (col0 + jl)];
            Bh[kl][jl] = Wh[(long)(k0 + kl) * D + (col0 + jl)];
        }
        __syncthreads();
#pragma unroll
        for (int k = 0; k < 16; ++k) {
            float az[4], ah[4], bzv[4], bhv[4];
#pragma unroll
            for (int i = 0; i < 4; ++i) { az[i] = Az[k][ty * 4 + i]; ah[i] = Ah[k][ty * 4 + i]; }
#pragma unroll
            for (int j = 0; j < 4; ++j) { bzv[j] = Bz[k][tx * 4 + j]; bhv[j] = Bh[k][tx * 4 + j]; }
#pragma unroll
            for (int i = 0; i < 4; ++i)
#pragma unroll
                for (int j = 0; j < 4; ++j) {
                    accz[i][j] += az[i] * bzv[j];
                    acch[i][j] += ah[i] * bhv[j];
                }
        }
        __syncthreads();
    }
#pragma unroll
    for (int i = 0; i < 4; ++i) {
        int r = row0 + ty * 4 + i;
        if (r >= rows) continue;
#pragma unroll
        for (int j = 0; j < 4; ++j) {
            int c = col0 + tx * 4 + j;
            float z = 1.f / (1.f + __expf(-(accz[i][j] + bz[c])));
            float hh = tanhf(acch[i][j] + bh[c]);
            float hv = Hin[(long)r * D + c];
            Out[(long)r * D + c] = (1.f - z) * hv + z * hh;
        }
    }
}

// ---------------- alpha_s / alpha_d per (node, head) ----------------
__global__ void alpha_k(const float* __restrict__ XP,
                        const float* __restrict__ a_s, const float* __restrict__ a_d,
                        float* __restrict__ AS, float* __restrict__ AD,
                        int Nn, int H, int C)
{
    int i = blockIdx.x * blockDim.x + threadIdx.x;
    if (i >= Nn * H) return;
    int n = i / H, h = i % H;
    const float* xp = &XP[(long)n * H * C + (long)h * C];
    float ss = 0.f, sd = 0.f;
    for (int c = 0; c < C; ++c) {
        float v = xp[c];
        ss += v * a_s[h * C + c];
        sd += v * a_d[h * C + c];
    }
    AS[i] = ss; AD[i] = sd;
}

// ---------------- CSR build ----------------
__global__ void count_k(const int* __restrict__ dst, int E, int* __restrict__ cnt)
{
    int e = blockIdx.x * blockDim.x + threadIdx.x;
    if (e < E) atomicAdd(&cnt[dst[e]], 1);
}

__global__ __launch_bounds__(1024) void scan_k(const int* __restrict__ cnt, int Nn,
                                               int* __restrict__ off)
{
    __shared__ int part[1024];
    int tid = threadIdx.x;
    int chunk = (Nn + 1023) / 1024;
    int b = tid * chunk;
    int e = b + chunk; if (e > Nn) e = Nn; if (b > Nn) b = Nn;
    int s = 0;
    for (int i = b; i < e; ++i) s += cnt[i];
    part[tid] = s;
    __syncthreads();
    for (int d = 1; d < 1024; d <<= 1) {
        int v = (tid >= d) ? part[tid - d] : 0;
        __syncthreads();
        part[tid] += v;
        __syncthreads();
    }
    int run = tid ? part[tid - 1] : 0;
    for (int i = b; i < e; ++i) { off[i] = run; run += cnt[i]; }
    if (tid == 1023) off[Nn] = part[1023];
}

__global__ void scatter_k(const int* __restrict__ src, const int* __restrict__ dst, int E,
                          const int* __restrict__ off, int* __restrict__ cur,
                          int* __restrict__ csr_src)
{
    int e = blockIdx.x * blockDim.x + threadIdx.x;
    if (e < E) {
        int d = dst[e];
        int p = atomicAdd(&cur[d], 1);
        csr_src[off[d] + p] = src[e];
    }
}

// ---------------- fused GAT gather ----------------
__global__ void gat_gather(const int* __restrict__ off, const int* __restrict__ csr_src,
                           const float* __restrict__ XP,
                           const float* __restrict__ AS, const float* __restrict__ AD,
                           const float* __restrict__ bias,
                           float* __restrict__ Gout, int Nn, int H, int C, int do_elu)
{
    const int D = H * C;
    const int lpn = D >> 2;
    const int npw = 64 / lpn;
    int lane = threadIdx.x & 63;
    long wave = ((long)blockIdx.x * blockDim.x + threadIdx.x) >> 6;
    int sub = lane / lpn;
    int cl = lane % lpn;
    long n = wave * npw + sub;
    if (n >= Nn) return;
    int j = cl * 4;
    int h = j / C;
    float ad = AD[n * H + h];
    float v = AS[n * H + h] + ad;
    v = v > 0.f ? v : NEG_SLOPE * v;
    float w = __expf(v);
    float den = w;
    float4 xv = *(const float4*)&XP[(long)n * D + j];
    float4 acc;
    acc.x = w * xv.x; acc.y = w * xv.y; acc.z = w * xv.z; acc.w = w * xv.w;
    int b0 = off[n], b1 = off[n + 1];
    for (int i = b0; i < b1; ++i) {
        int s = csr_src[i];
        v = AS[s * H + h] + ad;
        v = v > 0.f ? v : NEG_SLOPE * v;
        w = __expf(v);
        den += w;
        xv = *(const float4*)&XP[(long)s * D + j];
        acc.x += w * xv.x; acc.y += w * xv.y; acc.z += w * xv.z; acc.w += w * xv.w;
    }
    float inv = 1.f / (den + 1e-16f);
    float4 bv = *(const float4*)&bias[j];
    float o0 = acc.x * inv + bv.x;
    float o1 = acc.y * inv + bv.y;
    float o2 = acc.z * inv + bv.z;
    float o3 = acc.w * inv + bv.w;
    if (do_elu) {
        o0 = o0 > 0.f ? o0 : expm1f(o0);
        o1 = o1 > 0.f ? o1 : expm1f(o1);
        o2 = o2 > 0.f ? o2 : expm1f(o2);
        o3 = o3 > 0.f ? o3 : expm1f(o3);
    }
    float4 ov; ov.x = o0; ov.y = o1; ov.z = o2; ov.w = o3;
    *(float4*)&Gout[(long)n * D + j] = ov;
}

static inline void launch_gather(const int* off, const int* csr, const float* XP,
                                 const float* AS, const float* AD, const float* bias,
                                 float* Gout, int Nn, int H, int C, int do_elu,
                                 hipStream_t stream)
{
    int D = H * C;
    int lpn = D >> 2;
    int npw = 64 / lpn;
    long waves = (Nn + npw - 1) / npw;
    long thr = waves * 64;
    int blocks = (int)((thr + 255) / 256);
    gat_gather<<<blocks, 256, 0, stream>>>(off, csr, XP, AS, AD, bias, Gout, Nn, H, C, do_elu);
}

extern "C" void kernel_launch(void* const* d_in, const int* in_sizes, int n_in,
                              void* d_out, int out_size, void* d_ws, size_t ws_size,
                              hipStream_t stream)
{
    const float* x    = (const float*)d_in[0];
    const int*   ei   = (const int*)  d_in[1];
    const float* W_tr = (const float*)d_in[2];
    const float* b_tr = (const float*)d_in[3];
    const float* W1   = (const float*)d_in[4];
    const float* as1  = (const float*)d_in[5];
    const float* ad1  = (const float*)d_in[6];
    const float* b1   = (const float*)d_in[7];
    const float* Wr1  = (const float*)d_in[8];
    const float* br1  = (const float*)d_in[9];
    const float* Wz1  = (const float*)d_in[10];
    const float* bz1  = (const float*)d_in[11];
    const float* Wh1  = (const float*)d_in[12];
    const float* bh1  = (const float*)d_in[13];
    const float* Wp2  = (const float*)d_in[14];
    const float* bp2  = (const float*)d_in[15];
    const float* W2   = (const float*)d_in[16];
    const float* as2  = (const float*)d_in[17];
    const float* ad2  = (const float*)d_in[18];
    const float* b2   = (const float*)d_in[19];
    const float* Wr2  = (const float*)d_in[20];
    const float* br2  = (const float*)d_in[21];
    const float* Wz2  = (const float*)d_in[22];
    const float* bz2  = (const float*)d_in[23];
    const float* Wh2  = (const float*)d_in[24];
    const float* bh2  = (const float*)d_in[25];
    const float* Wp3  = (const float*)d_in[26];
    const float* bp3  = (const float*)d_in[27];
    const float* W3   = (const float*)d_in[28];
    const float* as3  = (const float*)d_in[29];
    const float* ad3  = (const float*)d_in[30];
    const float* b3   = (const float*)d_in[31];
    const float* Wr3  = (const float*)d_in[32];
    const float* br3  = (const float*)d_in[33];
    const float* Wz3  = (const float*)d_in[34];
    const float* bz3  = (const float*)d_in[35];
    const float* Wh3  = (const float*)d_in[36];
    const float* bh3  = (const float*)d_in[37];

    const int Nn = in_sizes[0] / 128;   // 50000
    const int E  = in_sizes[1] / 2;     // 800000
    const int* srcp = ei;
    const int* dstp = ei + E;

    float* ws  = (float*)d_ws;
    float* X0  = ws;                          // [N,256]
    float* XP  = X0  + (size_t)Nn * 256;      // [N,256]
    float* G   = XP  + (size_t)Nn * 256;      // [N,256]
    float* R   = G   + (size_t)Nn * 256;      // [N,256]
    float* HIN = R   + (size_t)Nn * 256;      // [N,128]
    float* AS  = HIN + (size_t)Nn * 128;      // [N,8]
    float* AD  = AS  + (size_t)Nn * 8;        // [N,8]
    int*   ioff = (int*)(AD + (size_t)Nn * 8);// [N+1]
    int*   cnt  = ioff + (Nn + 1);            // [N]
    int*   cur  = cnt + Nn;                   // [N]
    int*   csr  = cur + Nn;                   // [E]

    dim3 blk(256);
    int rb  = (Nn + 63) / 64;    // fp32 tiles (layer 3)
    int rbm = (Nn + 127) / 128;  // mfma tiles

    // ---------- CSR build ----------
    hipMemsetAsync(cnt, 0, (size_t)Nn * 4, stream);
    hipMemsetAsync(cur, 0, (size_t)Nn * 4, stream);
    count_k<<<(E + 255) / 256, blk, 0, stream>>>(dstp, E, cnt);
    scan_k<<<1, 1024, 0, stream>>>(cnt, Nn, ioff);
    scatter_k<<<(E + 255) / 256, blk, 0, stream>>>(srcp, dstp, E, ioff, cur, csr);

    // stage 0: X0 = x @ W_tr + b_tr
    gemm_mfma<<<dim3(4, rbm), blk, 0, stream>>>(x, 128, nullptr, 0, W_tr, b_tr, X0, Nn, 256, 0);

    // ================= layer 1 (D=256, H=8, C=32) =================
    gemm_mfma<<<dim3(4, rbm), blk, 0, stream>>>(X0, 256, nullptr, 0, W1, nullptr, XP, Nn, 256, 0);
    alpha_k<<<(Nn * 8 + 255) / 256, blk, 0, stream>>>(XP, as1, ad1, AS, AD, Nn, 8, 32);
    launch_gather(ioff, csr, XP, AS, AD, b1, G, Nn, 8, 32, 1, stream);
    gemm_mfma<<<dim3(4, rbm), blk, 0, stream>>>(G, 256, X0, 256, Wr1, br1, R, Nn, 256, 1);
    gru_mfma<<<dim3(4, rbm), blk, 0, stream>>>(G, X0, R, 256, Wz1, bz1, Wh1, bh1, XP, Nn);

    float* cx    = XP;
    float* spare = X0;

    // ================= layer 2 (H=4, C=32, out 128) =================
    gemm_mfma<<<dim3(2, rbm), blk, 0, stream>>>(cx, 256, nullptr, 0, Wp2, bp2, HIN, Nn, 128, 0);
    gemm_mfma<<<dim3(2, rbm), blk, 0, stream>>>(cx, 256, nullptr, 0, W2, nullptr, spare, Nn, 128, 0);
    alpha_k<<<(Nn * 4 + 255) / 256, blk, 0, stream>>>(spare, as2, ad2, AS, AD, Nn, 4, 32);
    launch_gather(ioff, csr, spare, AS, AD, b2, G, Nn, 4, 32, 1, stream);
    gemm_mfma<<<dim3(2, rbm), blk, 0, stream>>>(G, 128, HIN, 128, Wr2, br2, R, Nn, 128, 1);
    gru_mfma<<<dim3(2, rbm), blk, 0, stream>>>(G, HIN, R, 128, Wz2, bz2, Wh2, bh2, cx, Nn);

    // ================= layer 3 (H=1, C=64, out 64) — fp32 =================
    gemm_k<<<dim3(1, rb), blk, 0, stream>>>(cx, 128, nullptr, 0, Wp3, bp3, HIN, Nn, 64, 0);
    gemm_k<<<dim3(1, rb), blk, 0, stream>>>(cx, 128, nullptr, 0, W3, nullptr, spare, Nn, 64, 0);
    alpha_k<<<(Nn + 255) / 256, blk, 0, stream>>>(spare, as3, ad3, AS, AD, Nn, 1, 64);
    launch_gather(ioff, csr, spare, AS, AD, b3, G, Nn, 1, 64, 0, stream);
    gemm_k<<<dim3(1, rb), blk, 0, stream>>>(G, 64, HIN, 64, Wr3, br3, R, Nn, 64, 1);
    gru_fused_k<<<dim3(1, rb), blk, 0, stream>>>(G, HIN, R, 64, Wz3, bz3, Wh3, bh3, (float*)d_out, Nn);
}

// Round 4
// 1016.312 us; speedup vs baseline: 7.1915x; 1.0422x over previous
//
#include <hip/hip_runtime.h>

#define NEG_SLOPE 0.2f

typedef __attribute__((ext_vector_type(8))) short short8;
typedef __attribute__((ext_vector_type(8))) unsigned short ushort8;
typedef __attribute__((ext_vector_type(4))) float f32x4;

__device__ __forceinline__ unsigned short f2bf(float f) {
    unsigned int u = __float_as_uint(f);
    u += 0x7fff + ((u >> 16) & 1);     // round-to-nearest-even
    return (unsigned short)(u >> 16);
}
__device__ __forceinline__ float bf2f(unsigned short s) {
    return __uint_as_float(((unsigned int)s) << 16);
}

// ---------------- converters ----------------
__global__ void conv_k(const float* __restrict__ in, unsigned short* __restrict__ out, long n)
{
    long i = ((long)blockIdx.x * blockDim.x + threadIdx.x) * 4;
    if (i >= n) return;
    float4 f = *(const float4*)&in[i];
    ushort4 o; o.x = f2bf(f.x); o.y = f2bf(f.y); o.z = f2bf(f.z); o.w = f2bf(f.w);
    *(ushort4*)&out[i] = o;
}

// weights: W[K][Mo] fp32 -> Wc[(k>>3)*Mo + m][8] bf16 (swizzled for 16B B-staging)
__global__ void convW_k(const float* __restrict__ W, unsigned short* __restrict__ Wc,
                        int K, int Mo)
{
    int i = blockIdx.x * blockDim.x + threadIdx.x;
    if (i >= K * Mo) return;
    int k = i / Mo, m = i % Mo;
    Wc[((long)(k >> 3) * Mo + m) * 8 + (k & 7)] = f2bf(W[i]);
}

// ================= bf16 MFMA GEMM =================
// A = [U | V] bf16 row-major; Wc swizzled bf16; BM=128 BN=64 BK=32, 4 waves.
// mode 0: outF/outB = acc+bias (either may be null)
// mode 1: outB = bf16( sigmoid(acc+bias) * HinF[row,col] )   (r-gate fused)
__global__ __launch_bounds__(256) void gemm_b(
    const unsigned short* __restrict__ U, int K1,
    const unsigned short* __restrict__ V, int K2,
    const unsigned short* __restrict__ Wc, const float* __restrict__ bias,
    float* __restrict__ outF, unsigned short* __restrict__ outB,
    const float* __restrict__ HinF,
    int rows, int Mo, int mode)
{
    __shared__ __align__(16) unsigned short As[4][128][8];
    __shared__ __align__(16) unsigned short Bs[4][64][8];
    const int tid = threadIdx.x;
    const int row0 = blockIdx.y * 128;
    const int col0 = blockIdx.x * 64;
    const int K = K1 + K2;
    const int l = tid & 63, w = tid >> 6;
    const int lm = l & 15, lg = l >> 4;
    f32x4 acc[2][4] = {};

    for (int k0 = 0; k0 < K; k0 += 32) {
#pragma unroll
        for (int c = tid; c < 512; c += 256) {
            int m = c & 127, g = c >> 7;
            int row = row0 + m, k = k0 + g * 8;
            ushort8 v = {0,0,0,0,0,0,0,0};
            if (row < rows) {
                const unsigned short* sp = (k < K1) ? U + (long)row * K1 + k
                                                    : V + (long)row * K2 + (k - K1);
                v = *(const ushort8*)sp;
            }
            *(ushort8*)&As[g][m][0] = v;
        }
        {
            int n = tid & 63, g = tid >> 6;
            const unsigned short* wp = Wc + ((long)((k0 >> 3) + g) * Mo + (col0 + n)) * 8;
            *(ushort8*)&Bs[g][n][0] = *(const ushort8*)wp;
        }
        __syncthreads();
        short8 a[2], b[4];
#pragma unroll
        for (int mi = 0; mi < 2; ++mi)
            a[mi] = *(const short8*)&As[lg][w * 32 + mi * 16 + lm][0];
#pragma unroll
        for (int ni = 0; ni < 4; ++ni)
            b[ni] = *(const short8*)&Bs[lg][ni * 16 + lm][0];
#pragma unroll
        for (int mi = 0; mi < 2; ++mi)
#pragma unroll
            for (int ni = 0; ni < 4; ++ni)
                acc[mi][ni] = __builtin_amdgcn_mfma_f32_16x16x32_bf16(a[mi], b[ni], acc[mi][ni], 0, 0, 0);
        __syncthreads();
    }
#pragma unroll
    for (int mi = 0; mi < 2; ++mi) {
        int rbase = row0 + w * 32 + mi * 16 + lg * 4;
#pragma unroll
        for (int r = 0; r < 4; ++r) {
            int row = rbase + r;
            if (row >= rows) continue;
#pragma unroll
            for (int ni = 0; ni < 4; ++ni) {
                int col = col0 + ni * 16 + lm;
                float v = acc[mi][ni][r] + (bias ? bias[col] : 0.f);
                if (mode == 1) {
                    float rr = 1.f / (1.f + __expf(-v));
                    outB[(long)row * Mo + col] = f2bf(rr * HinF[(long)row * Mo + col]);
                } else {
                    if (outF) outF[(long)row * Mo + col] = v;
                    if (outB) outB[(long)row * Mo + col] = f2bf(v);
                }
            }
        }
    }
}

// ================= bf16 MFMA fused GRU (phase-split) =================
// accz = [G|Hin]@Wz, acch = [G|RH]@Wh ; Out = (1-z)*HinF + z*tanh(acch+bh)
__global__ __launch_bounds__(256) void gru_b(
    const unsigned short* __restrict__ Gb, const unsigned short* __restrict__ Hb,
    const unsigned short* __restrict__ RHb, const float* __restrict__ HinF, int D,
    const unsigned short* __restrict__ Wzc, const float* __restrict__ bz,
    const unsigned short* __restrict__ Whc, const float* __restrict__ bh,
    float* __restrict__ outF, unsigned short* __restrict__ outB, int rows)
{
    __shared__ __align__(16) unsigned short As0[4][128][8];
    __shared__ __align__(16) unsigned short As1[4][128][8];
    __shared__ __align__(16) unsigned short Bsz[4][64][8];
    __shared__ __align__(16) unsigned short Bsh[4][64][8];
    const int tid = threadIdx.x;
    const int row0 = blockIdx.y * 128;
    const int col0 = blockIdx.x * 64;
    const int l = tid & 63, w = tid >> 6;
    const int lm = l & 15, lg = l >> 4;
    f32x4 accz[2][4] = {}, acch[2][4] = {};

    // -------- phase 1: k in [0,D), A = G (shared by z and h) --------
    for (int k0 = 0; k0 < D; k0 += 32) {
#pragma unroll
        for (int c = tid; c < 512; c += 256) {
            int m = c & 127, g = c >> 7;
            int row = row0 + m, k = k0 + g * 8;
            ushort8 v = {0,0,0,0,0,0,0,0};
            if (row < rows) v = *(const ushort8*)(Gb + (long)row * D + k);
            *(ushort8*)&As0[g][m][0] = v;
        }
        {
            int n = tid & 63, g = tid >> 6;
            long base = ((long)((k0 >> 3) + g) * D + (col0 + n)) * 8;
            *(ushort8*)&Bsz[g][n][0] = *(const ushort8*)(Wzc + base);
            *(ushort8*)&Bsh[g][n][0] = *(const ushort8*)(Whc + base);
        }
        __syncthreads();
        short8 a[2], bzv[4], bhv[4];
#pragma unroll
        for (int mi = 0; mi < 2; ++mi)
            a[mi] = *(const short8*)&As0[lg][w * 32 + mi * 16 + lm][0];
#pragma unroll
        for (int ni = 0; ni < 4; ++ni) {
            bzv[ni] = *(const short8*)&Bsz[lg][ni * 16 + lm][0];
            bhv[ni] = *(const short8*)&Bsh[lg][ni * 16 + lm][0];
        }
#pragma unroll
        for (int mi = 0; mi < 2; ++mi)
#pragma unroll
            for (int ni = 0; ni < 4; ++ni) {
                accz[mi][ni] = __builtin_amdgcn_mfma_f32_16x16x32_bf16(a[mi], bzv[ni], accz[mi][ni], 0, 0, 0);
                acch[mi][ni] = __builtin_amdgcn_mfma_f32_16x16x32_bf16(a[mi], bhv[ni], acch[mi][ni], 0, 0, 0);
            }
        __syncthreads();
    }
    // -------- phase 2: k in [D,2D), Az = Hin, Ah = R*Hin --------
    for (int k0 = 0; k0 < D; k0 += 32) {
#pragma unroll
        for (int c = tid; c < 512; c += 256) {
            int m = c & 127, g = c >> 7;
            int row = row0 + m, k = k0 + g * 8;
            ushort8 v0 = {0,0,0,0,0,0,0,0}, v1 = v0;
            if (row < rows) {
                v0 = *(const ushort8*)(Hb  + (long)row * D + k);
                v1 = *(const ushort8*)(RHb + (long)row * D + k);
            }
            *(ushort8*)&As0[g][m][0] = v0;
            *(ushort8*)&As1[g][m][0] = v1;
        }
        {
            int n = tid & 63, g = tid >> 6;
            long base = ((long)(((D + k0) >> 3) + g) * D + (col0 + n)) * 8;
            *(ushort8*)&Bsz[g][n][0] = *(const ushort8*)(Wzc + base);
            *(ushort8*)&Bsh[g][n][0] = *(const ushort8*)(Whc + base);
        }
        __syncthreads();
        short8 az[2], ah[2], bzv[4], bhv[4];
#pragma unroll
        for (int mi = 0; mi < 2; ++mi) {
            az[mi] = *(const short8*)&As0[lg][w * 32 + mi * 16 + lm][0];
            ah[mi] = *(const short8*)&As1[lg][w * 32 + mi * 16 + lm][0];
        }
#pragma unroll
        for (int ni = 0; ni < 4; ++ni) {
            bzv[ni] = *(const short8*)&Bsz[lg][ni * 16 + lm][0];
            bhv[ni] = *(const short8*)&Bsh[lg][ni * 16 + lm][0];
        }
#pragma unroll
        for (int mi = 0; mi < 2; ++mi)
#pragma unroll
            for (int ni = 0; ni < 4; ++ni) {
                accz[mi][ni] = __builtin_amdgcn_mfma_f32_16x16x32_bf16(az[mi], bzv[ni], accz[mi][ni], 0, 0, 0);
                acch[mi][ni] = __builtin_amdgcn_mfma_f32_16x16x32_bf16(ah[mi], bhv[ni], acch[mi][ni], 0, 0, 0);
            }
        __syncthreads();
    }
#pragma unroll
    for (int mi = 0; mi < 2; ++mi) {
        int rbase = row0 + w * 32 + mi * 16 + lg * 4;
#pragma unroll
        for (int r = 0; r < 4; ++r) {
            int row = rbase + r;
            if (row >= rows) continue;
#pragma unroll
            for (int ni = 0; ni < 4; ++ni) {
                int col = col0 + ni * 16 + lm;
                float z  = 1.f / (1.f + __expf(-(accz[mi][ni][r] + bz[col])));
                float hh = tanhf(acch[mi][ni][r] + bh[col]);
                float hv = HinF[(long)row * D + col];
                float o  = (1.f - z) * hv + z * hh;
                if (outF) outF[(long)row * D + col] = o;
                if (outB) outB[(long)row * D + col] = f2bf(o);
            }
        }
    }
}

// ================= fp32 tiled SGEMM (layer-3) =================
__global__ __launch_bounds__(256) void gemm_k(
    const float* __restrict__ U, int K1,
    const float* __restrict__ V, int K2,
    const float* __restrict__ W, const float* __restrict__ bias,
    float* __restrict__ Cout, int rows, int Mo, int act)
{
    __shared__ float As[16][65];
    __shared__ float Bs[16][64];
    const int tid = threadIdx.x;
    const int row0 = blockIdx.y * 64;
    const int col0 = blockIdx.x * 64;
    const int tx = tid & 15, ty = tid >> 4;
    const int K = K1 + K2;
    float acc[4][4] = {};
    for (int k0 = 0; k0 < K; k0 += 16) {
#pragma unroll
        for (int i = 0; i < 4; ++i) {
            int idx = tid + i * 256;
            int rl = idx >> 4, kl = idx & 15;
            int r = row0 + rl, k = k0 + kl;
            float v = 0.f;
            if (r < rows) {
                if (k < K1) v = U[(long)r * K1 + k];
                else        v = V[(long)r * K2 + (k - K1)];
            }
            As[kl][rl] = v;
        }
#pragma unroll
        for (int i = 0; i < 4; ++i) {
            int idx = tid + i * 256;
            int kl = idx >> 6, jl = idx & 63;
            Bs[kl][jl] = W[(long)(k0 + kl) * Mo + (col0 + jl)];
        }
        __syncthreads();
#pragma unroll
        for (int k = 0; k < 16; ++k) {
            float a[4], b[4];
#pragma unroll
            for (int i = 0; i < 4; ++i) a[i] = As[k][ty * 4 + i];
#pragma unroll
            for (int j = 0; j < 4; ++j) b[j] = Bs[k][tx * 4 + j];
#pragma unroll
            for (int i = 0; i < 4; ++i)
#pragma unroll
                for (int j = 0; j < 4; ++j)
                    acc[i][j] += a[i] * b[j];
        }
        __syncthreads();
    }
#pragma unroll
    for (int i = 0; i < 4; ++i) {
        int r = row0 + ty * 4 + i;
        if (r >= rows) continue;
#pragma unroll
        for (int j = 0; j < 4; ++j) {
            int c = col0 + tx * 4 + j;
            float v = acc[i][j] + (bias ? bias[c] : 0.f);
            if (act == 1) v = 1.f / (1.f + __expf(-v));
            Cout[(long)r * Mo + c] = v;
        }
    }
}

// ---------------- fp32 fused GRU (layer 3) ----------------
__global__ __launch_bounds__(256) void gru_fused_k(
    const float* __restrict__ Gp, const float* __restrict__ Hin,
    const float* __restrict__ Rp, int D,
    const float* __restrict__ Wz, const float* __restrict__ bz,
    const float* __restrict__ Wh, const float* __restrict__ bh,
    float* __restrict__ Out, int rows)
{
    __shared__ float Az[16][65];
    __shared__ float Ah[16][65];
    __shared__ float Bz[16][64];
    __shared__ float Bh[16][64];
    const int tid = threadIdx.x;
    const int row0 = blockIdx.y * 64;
    const int col0 = blockIdx.x * 64;
    const int tx = tid & 15, ty = tid >> 4;
    const int K = 2 * D;
    float accz[4][4] = {}, acch[4][4] = {};
    for (int k0 = 0; k0 < K; k0 += 16) {
#pragma unroll
        for (int i = 0; i < 4; ++i) {
            int idx = tid + i * 256;
            int rl = idx >> 4, kl = idx & 15;
            int r = row0 + rl, k = k0 + kl;
            float vz = 0.f, vh = 0.f;
            if (r < rows) {
                if (k < D) { vz = Gp[(long)r * D + k]; vh = vz; }
                else {
                    int k2 = k - D;
                    float hv = Hin[(long)r * D + k2];
                    vz = hv; vh = hv * Rp[(long)r * D + k2];
                }
            }
            Az[kl][rl] = vz; Ah[kl][rl] = vh;
        }
#pragma unroll
        for (int i = 0; i < 4; ++i) {
            int idx = tid + i * 256;
            int kl = idx >> 6, jl = idx & 63;
            Bz[kl][jl] = Wz[(long)(k0 + kl) * D + (col0 + jl)];
            Bh[kl][jl] = Wh[(long)(k0 + kl) * D + (col0 + jl)];
        }
        __syncthreads();
#pragma unroll
        for (int k = 0; k < 16; ++k) {
            float az[4], ah[4], bzv[4], bhv[4];
#pragma unroll
            for (int i = 0; i < 4; ++i) { az[i] = Az[k][ty * 4 + i]; ah[i] = Ah[k][ty * 4 + i]; }
#pragma unroll
            for (int j = 0; j < 4; ++j) { bzv[j] = Bz[k][tx * 4 + j]; bhv[j] = Bh[k][tx * 4 + j]; }
#pragma unroll
            for (int i = 0; i < 4; ++i)
#pragma unroll
                for (int j = 0; j < 4; ++j) {
                    accz[i][j] += az[i] * bzv[j];
                    acch[i][j] += ah[i] * bhv[j];
                }
        }
        __syncthreads();
    }
#pragma unroll
    for (int i = 0; i < 4; ++i) {
        int r = row0 + ty * 4 + i;
        if (r >= rows) continue;
#pragma unroll
        for (int j = 0; j < 4; ++j) {
            int c = col0 + tx * 4 + j;
            float z = 1.f / (1.f + __expf(-(accz[i][j] + bz[c])));
            float hh = tanhf(acch[i][j] + bh[c]);
            float hv = Hin[(long)r * D + c];
            Out[(long)r * D + c] = (1.f - z) * hv + z * hh;
        }
    }
}

// ---------------- alpha (bf16 / fp32 inputs) ----------------
__global__ void alpha_b(const unsigned short* __restrict__ XPb,
                        const float* __restrict__ a_s, const float* __restrict__ a_d,
                        float* __restrict__ AS, float* __restrict__ AD,
                        int Nn, int H, int C)
{
    int i = blockIdx.x * blockDim.x + threadIdx.x;
    if (i >= Nn * H) return;
    int n = i / H, h = i % H;
    const unsigned short* xp = &XPb[(long)n * H * C + (long)h * C];
    float ss = 0.f, sd = 0.f;
    for (int c = 0; c < C; ++c) {
        float v = bf2f(xp[c]);
        ss += v * a_s[h * C + c];
        sd += v * a_d[h * C + c];
    }
    AS[i] = ss; AD[i] = sd;
}

__global__ void alpha_k(const float* __restrict__ XP,
                        const float* __restrict__ a_s, const float* __restrict__ a_d,
                        float* __restrict__ AS, float* __restrict__ AD,
                        int Nn, int H, int C)
{
    int i = blockIdx.x * blockDim.x + threadIdx.x;
    if (i >= Nn * H) return;
    int n = i / H, h = i % H;
    const float* xp = &XP[(long)n * H * C + (long)h * C];
    float ss = 0.f, sd = 0.f;
    for (int c = 0; c < C; ++c) {
        float v = xp[c];
        ss += v * a_s[h * C + c];
        sd += v * a_d[h * C + c];
    }
    AS[i] = ss; AD[i] = sd;
}

// ---------------- CSR build ----------------
__global__ void count_k(const int* __restrict__ dst, int E, int* __restrict__ cnt)
{
    int e = blockIdx.x * blockDim.x + threadIdx.x;
    if (e < E) atomicAdd(&cnt[dst[e]], 1);
}

__global__ __launch_bounds__(1024) void scan_k(const int* __restrict__ cnt, int Nn,
                                               int* __restrict__ off)
{
    __shared__ int part[1024];
    int tid = threadIdx.x;
    int chunk = (Nn + 1023) / 1024;
    int b = tid * chunk;
    int e = b + chunk; if (e > Nn) e = Nn; if (b > Nn) b = Nn;
    int s = 0;
    for (int i = b; i < e; ++i) s += cnt[i];
    part[tid] = s;
    __syncthreads();
    for (int d = 1; d < 1024; d <<= 1) {
        int v = (tid >= d) ? part[tid - d] : 0;
        __syncthreads();
        part[tid] += v;
        __syncthreads();
    }
    int run = tid ? part[tid - 1] : 0;
    for (int i = b; i < e; ++i) { off[i] = run; run += cnt[i]; }
    if (tid == 1023) off[Nn] = part[1023];
}

__global__ void scatter_k(const int* __restrict__ src, const int* __restrict__ dst, int E,
                          const int* __restrict__ off, int* __restrict__ cur,
                          int* __restrict__ csr_src)
{
    int e = blockIdx.x * blockDim.x + threadIdx.x;
    if (e < E) {
        int d = dst[e];
        int p = atomicAdd(&cur[d], 1);
        csr_src[off[d] + p] = src[e];
    }
}

// ---------------- bf16 GAT gather (8 feats/lane) ----------------
__global__ void gat_gather_b(const int* __restrict__ off, const int* __restrict__ csr_src,
                             const unsigned short* __restrict__ XPb,
                             const float* __restrict__ AS, const float* __restrict__ AD,
                             const float* __restrict__ bias,
                             unsigned short* __restrict__ Gout,
                             int Nn, int H, int C, int do_elu)
{
    const int D = H * C;
    const int lpn = D >> 3;
    const int npw = 64 / lpn;
    int lane = threadIdx.x & 63;
    long wave = ((long)blockIdx.x * blockDim.x + threadIdx.x) >> 6;
    int sub = lane / lpn;
    int cl = lane % lpn;
    long n = wave * npw + sub;
    if (n >= Nn) return;
    int j = cl * 8;
    int h = j / C;
    float ad = AD[n * H + h];
    float v = AS[n * H + h] + ad;
    v = v > 0.f ? v : NEG_SLOPE * v;
    float w = __expf(v);
    float den = w;
    float acc[8];
    {
        ushort8 xv = *(const ushort8*)&XPb[(long)n * D + j];
#pragma unroll
        for (int q = 0; q < 8; ++q) acc[q] = w * bf2f(xv[q]);
    }
    int b0 = off[n], b1 = off[n + 1];
    for (int i = b0; i < b1; ++i) {
        int s = csr_src[i];
        v = AS[s * H + h] + ad;
        v = v > 0.f ? v : NEG_SLOPE * v;
        w = __expf(v);
        den += w;
        ushort8 xv = *(const ushort8*)&XPb[(long)s * D + j];
#pragma unroll
        for (int q = 0; q < 8; ++q) acc[q] += w * bf2f(xv[q]);
    }
    float inv = 1.f / (den + 1e-16f);
    ushort8 ov;
#pragma unroll
    for (int q = 0; q < 8; ++q) {
        float o = acc[q] * inv + bias[j + q];
        if (do_elu) o = o > 0.f ? o : expm1f(o);
        ov[q] = f2bf(o);
    }
    *(ushort8*)&Gout[(long)n * D + j] = ov;
}

// ---------------- fp32 GAT gather (layer 3) ----------------
__global__ void gat_gather(const int* __restrict__ off, const int* __restrict__ csr_src,
                           const float* __restrict__ XP,
                           const float* __restrict__ AS, const float* __restrict__ AD,
                           const float* __restrict__ bias,
                           float* __restrict__ Gout, int Nn, int H, int C, int do_elu)
{
    const int D = H * C;
    const int lpn = D >> 2;
    const int npw = 64 / lpn;
    int lane = threadIdx.x & 63;
    long wave = ((long)blockIdx.x * blockDim.x + threadIdx.x) >> 6;
    int sub = lane / lpn;
    int cl = lane % lpn;
    long n = wave * npw + sub;
    if (n >= Nn) return;
    int j = cl * 4;
    int h = j / C;
    float ad = AD[n * H + h];
    float v = AS[n * H + h] + ad;
    v = v > 0.f ? v : NEG_SLOPE * v;
    float w = __expf(v);
    float den = w;
    float4 xv = *(const float4*)&XP[(long)n * D + j];
    float4 acc;
    acc.x = w * xv.x; acc.y = w * xv.y; acc.z = w * xv.z; acc.w = w * xv.w;
    int b0 = off[n], b1 = off[n + 1];
    for (int i = b0; i < b1; ++i) {
        int s = csr_src[i];
        v = AS[s * H + h] + ad;
        v = v > 0.f ? v : NEG_SLOPE * v;
        w = __expf(v);
        den += w;
        xv = *(const float4*)&XP[(long)s * D + j];
        acc.x += w * xv.x; acc.y += w * xv.y; acc.z += w * xv.z; acc.w += w * xv.w;
    }
    float inv = 1.f / (den + 1e-16f);
    float4 bv = *(const float4*)&bias[j];
    float o0 = acc.x * inv + bv.x;
    float o1 = acc.y * inv + bv.y;
    float o2 = acc.z * inv + bv.z;
    float o3 = acc.w * inv + bv.w;
    if (do_elu) {
        o0 = o0 > 0.f ? o0 : expm1f(o0);
        o1 = o1 > 0.f ? o1 : expm1f(o1);
        o2 = o2 > 0.f ? o2 : expm1f(o2);
        o3 = o3 > 0.f ? o3 : expm1f(o3);
    }
    float4 ov; ov.x = o0; ov.y = o1; ov.z = o2; ov.w = o3;
    *(float4*)&Gout[(long)n * D + j] = ov;
}

extern "C" void kernel_launch(void* const* d_in, const int* in_sizes, int n_in,
                              void* d_out, int out_size, void* d_ws, size_t ws_size,
                              hipStream_t stream)
{
    const float* x    = (const float*)d_in[0];
    const int*   ei   = (const int*)  d_in[1];
    const float* W_tr = (const float*)d_in[2];
    const float* b_tr = (const float*)d_in[3];
    const float* W1   = (const float*)d_in[4];
    const float* as1  = (const float*)d_in[5];
    const float* ad1  = (const float*)d_in[6];
    const float* b1   = (const float*)d_in[7];
    const float* Wr1  = (const float*)d_in[8];
    const float* br1  = (const float*)d_in[9];
    const float* Wz1  = (const float*)d_in[10];
    const float* bz1  = (const float*)d_in[11];
    const float* Wh1  = (const float*)d_in[12];
    const float* bh1  = (const float*)d_in[13];
    const float* Wp2  = (const float*)d_in[14];
    const float* bp2  = (const float*)d_in[15];
    const float* W2   = (const float*)d_in[16];
    const float* as2  = (const float*)d_in[17];
    const float* ad2  = (const float*)d_in[18];
    const float* b2   = (const float*)d_in[19];
    const float* Wr2  = (const float*)d_in[20];
    const float* br2  = (const float*)d_in[21];
    const float* Wz2  = (const float*)d_in[22];
    const float* bz2  = (const float*)d_in[23];
    const float* Wh2  = (const float*)d_in[24];
    const float* bh2  = (const float*)d_in[25];
    const float* Wp3  = (const float*)d_in[26];
    const float* bp3  = (const float*)d_in[27];
    const float* W3   = (const float*)d_in[28];
    const float* as3  = (const float*)d_in[29];
    const float* ad3  = (const float*)d_in[30];
    const float* b3   = (const float*)d_in[31];
    const float* Wr3  = (const float*)d_in[32];
    const float* br3  = (const float*)d_in[33];
    const float* Wz3  = (const float*)d_in[34];
    const float* bz3  = (const float*)d_in[35];
    const float* Wh3  = (const float*)d_in[36];
    const float* bh3  = (const float*)d_in[37];

    const int Nn = in_sizes[0] / 128;   // 50000
    const int E  = in_sizes[1] / 2;     // 800000
    const int* srcp = ei;
    const int* dstp = ei + E;

    // ---------------- workspace layout ----------------
    float* X0f  = (float*)d_ws;                         // [N,256] (layer3 reuses as 4x[N,64])
    float* HINf = X0f  + (size_t)Nn * 256;              // [N,128]
    float* CX2f = HINf + (size_t)Nn * 128;              // [N,128]
    float* AS   = CX2f + (size_t)Nn * 128;              // [N,8]
    float* AD   = AS   + (size_t)Nn * 8;                // [N,8]
    unsigned short* X0b  = (unsigned short*)(AD + (size_t)Nn * 8); // [N,256] (L2: XP2b)
    unsigned short* XPb  = X0b + (size_t)Nn * 256;      // [N,256] (L1 gru out CX1b)
    unsigned short* Gb   = XPb + (size_t)Nn * 256;      // [N,256] (also xb at start)
    unsigned short* RHb  = Gb  + (size_t)Nn * 256;      // [N,256]
    unsigned short* HINb = RHb + (size_t)Nn * 256;      // [N,128]
    unsigned short* wpool = HINb + (size_t)Nn * 128;    // weights, ~656K elems
    unsigned short* Wtrc = wpool;                       // 128*256
    unsigned short* W1c  = Wtrc + 128 * 256;            // 256*256
    unsigned short* Wr1c = W1c  + 256 * 256;            // 512*256
    unsigned short* Wz1c = Wr1c + 512 * 256;
    unsigned short* Wh1c = Wz1c + 512 * 256;
    unsigned short* Wp2c = Wh1c + 512 * 256;            // 256*128
    unsigned short* W2c  = Wp2c + 256 * 128;
    unsigned short* Wr2c = W2c  + 256 * 128;
    unsigned short* Wz2c = Wr2c + 256 * 128;
    unsigned short* Wh2c = Wz2c + 256 * 128;
    int* ioff = (int*)(((size_t)(Wh2c + 256 * 128) + 15) & ~(size_t)15);
    int* cnt  = ioff + (Nn + 1);
    int* cur  = cnt + Nn;
    int* csr  = cur + Nn;

    dim3 blk(256);
    int rb  = (Nn + 63) / 64;
    int rbm = (Nn + 127) / 128;

    // ---------- weight conversion (swizzled) ----------
    convW_k<<<(128*256 + 255) / 256, blk, 0, stream>>>(W_tr, Wtrc, 128, 256);
    convW_k<<<(256*256 + 255) / 256, blk, 0, stream>>>(W1,  W1c,  256, 256);
    convW_k<<<(512*256 + 255) / 256, blk, 0, stream>>>(Wr1, Wr1c, 512, 256);
    convW_k<<<(512*256 + 255) / 256, blk, 0, stream>>>(Wz1, Wz1c, 512, 256);
    convW_k<<<(512*256 + 255) / 256, blk, 0, stream>>>(Wh1, Wh1c, 512, 256);
    convW_k<<<(256*128 + 255) / 256, blk, 0, stream>>>(Wp2, Wp2c, 256, 128);
    convW_k<<<(256*128 + 255) / 256, blk, 0, stream>>>(W2,  W2c,  256, 128);
    convW_k<<<(256*128 + 255) / 256, blk, 0, stream>>>(Wr2, Wr2c, 256, 128);
    convW_k<<<(256*128 + 255) / 256, blk, 0, stream>>>(Wz2, Wz2c, 256, 128);
    convW_k<<<(256*128 + 255) / 256, blk, 0, stream>>>(Wh2, Wh2c, 256, 128);

    // ---------- CSR build ----------
    hipMemsetAsync(cnt, 0, (size_t)Nn * 4, stream);
    hipMemsetAsync(cur, 0, (size_t)Nn * 4, stream);
    count_k<<<(E + 255) / 256, blk, 0, stream>>>(dstp, E, cnt);
    scan_k<<<1, 1024, 0, stream>>>(cnt, Nn, ioff);
    scatter_k<<<(E + 255) / 256, blk, 0, stream>>>(srcp, dstp, E, ioff, cur, csr);

    // ---------- stage 0: x -> bf16, X0 = x @ W_tr + b_tr (dual write) ----------
    unsigned short* xb = Gb;   // Gb free until gather1
    conv_k<<<(int)(((long)Nn * 128 / 4 + 255) / 256), blk, 0, stream>>>(x, xb, (long)Nn * 128);
    gemm_b<<<dim3(4, rbm), blk, 0, stream>>>(xb, 128, nullptr, 0, Wtrc, b_tr, X0f, X0b, nullptr, Nn, 256, 0);

    // ================= layer 1 (D=256, H=8, C=32) =================
    gemm_b<<<dim3(4, rbm), blk, 0, stream>>>(X0b, 256, nullptr, 0, W1c, nullptr, nullptr, XPb, nullptr, Nn, 256, 0);
    alpha_b<<<(Nn * 8 + 255) / 256, blk, 0, stream>>>(XPb, as1, ad1, AS, AD, Nn, 8, 32);
    {
        long waves = (Nn + 1) / 2;  // npw=2
        gat_gather_b<<<(int)((waves * 64 + 255) / 256), blk, 0, stream>>>(ioff, csr, XPb, AS, AD, b1, Gb, Nn, 8, 32, 1);
    }
    gemm_b<<<dim3(4, rbm), blk, 0, stream>>>(Gb, 256, X0b, 256, Wr1c, br1, nullptr, RHb, X0f, Nn, 256, 1);
    gru_b<<<dim3(4, rbm), blk, 0, stream>>>(Gb, X0b, RHb, X0f, 256, Wz1c, bz1, Wh1c, bh1, nullptr, XPb, Nn);
    // XPb now holds x1 (bf16)

    // ================= layer 2 (D=128) =================
    gemm_b<<<dim3(2, rbm), blk, 0, stream>>>(XPb, 256, nullptr, 0, Wp2c, bp2, HINf, HINb, nullptr, Nn, 128, 0);
    gemm_b<<<dim3(2, rbm), blk, 0, stream>>>(XPb, 256, nullptr, 0, W2c, nullptr, nullptr, X0b, nullptr, Nn, 128, 0);
    alpha_b<<<(Nn * 4 + 255) / 256, blk, 0, stream>>>(X0b, as2, ad2, AS, AD, Nn, 4, 32);
    {
        long waves = (Nn + 3) / 4;  // npw=4
        gat_gather_b<<<(int)((waves * 64 + 255) / 256), blk, 0, stream>>>(ioff, csr, X0b, AS, AD, b2, Gb, Nn, 4, 32, 1);
    }
    gemm_b<<<dim3(2, rbm), blk, 0, stream>>>(Gb, 128, HINb, 128, Wr2c, br2, nullptr, RHb, HINf, Nn, 128, 1);
    gru_b<<<dim3(2, rbm), blk, 0, stream>>>(Gb, HINb, RHb, HINf, 128, Wz2c, bz2, Wh2c, bh2, CX2f, nullptr, Nn);
    // CX2f holds x2 (fp32)

    // ================= layer 3 (fp32, D=64) =================
    float* H3  = X0f;
    float* XP3 = X0f + (size_t)Nn * 64;
    float* G3  = X0f + (size_t)Nn * 128;
    float* R3  = X0f + (size_t)Nn * 192;
    gemm_k<<<dim3(1, rb), blk, 0, stream>>>(CX2f, 128, nullptr, 0, Wp3, bp3, H3, Nn, 64, 0);
    gemm_k<<<dim3(1, rb), blk, 0, stream>>>(CX2f, 128, nullptr, 0, W3, nullptr, XP3, Nn, 64, 0);
    alpha_k<<<(Nn + 255) / 256, blk, 0, stream>>>(XP3, as3, ad3, AS, AD, Nn, 1, 64);
    {
        long waves = (Nn + 3) / 4;  // lpn=16, npw=4
        gat_gather<<<(int)((waves * 64 + 255) / 256), blk, 0, stream>>>(ioff, csr, XP3, AS, AD, b3, G3, Nn, 1, 64, 0);
    }
    gemm_k<<<dim3(1, rb), blk, 0, stream>>>(G3, 64, H3, 64, Wr3, br3, R3, Nn, 64, 1);
    gru_fused_k<<<dim3(1, rb), blk, 0, stream>>>(G3, H3, R3, 64, Wz3, bz3, Wh3, bh3, (float*)d_out, Nn);
}

// Round 5
// 954.193 us; speedup vs baseline: 7.6596x; 1.0651x over previous
//
#include <hip/hip_runtime.h>

#define NEG_SLOPE 0.2f

typedef __attribute__((ext_vector_type(8))) short short8;
typedef __attribute__((ext_vector_type(8))) unsigned short ushort8;
typedef __attribute__((ext_vector_type(4))) float f32x4;

__device__ __forceinline__ unsigned short f2bf(float f) {
    unsigned int u = __float_as_uint(f);
    u += 0x7fff + ((u >> 16) & 1);     // round-to-nearest-even
    return (unsigned short)(u >> 16);
}
__device__ __forceinline__ float bf2f(unsigned short s) {
    return __uint_as_float(((unsigned int)s) << 16);
}

// async global->LDS, 16B per lane; lds base must be wave-uniform
__device__ __forceinline__ void gll16(const void* g, void* l) {
    __builtin_amdgcn_global_load_lds(
        (const __attribute__((address_space(1))) void*)g,
        (__attribute__((address_space(3))) void*)l, 16, 0, 0);
}

// ---------------- converters ----------------
__global__ void conv_k(const float* __restrict__ in, unsigned short* __restrict__ out, long n)
{
    long i = ((long)blockIdx.x * blockDim.x + threadIdx.x) * 4;
    if (i >= n) return;
    float4 f = *(const float4*)&in[i];
    ushort4 o; o.x = f2bf(f.x); o.y = f2bf(f.y); o.z = f2bf(f.z); o.w = f2bf(f.w);
    *(ushort4*)&out[i] = o;
}

// all weights in one launch: W[K][Mo] fp32 -> Wc[(k>>3)*Mo + m][8] bf16
struct WPack {
    const float* W[10];
    unsigned short* Wc[10];
    int K[10];
    int Mo[10];
};
__global__ void convW_all(WPack p)
{
    int wi = blockIdx.y;
    int i = blockIdx.x * blockDim.x + threadIdx.x;
    int K = p.K[wi], Mo = p.Mo[wi];
    if (i >= K * Mo) return;
    int k = i / Mo, m = i % Mo;
    p.Wc[wi][((long)(k >> 3) * Mo + m) * 8 + (k & 7)] = f2bf(p.W[wi][i]);
}

// ================= bf16 MFMA GEMM (global_load_lds staging) =================
// A = [U | V] bf16 row-major; Wc swizzled bf16; BM=128 BN=64 BK=32, 4 waves.
// mode 0: outF/outB = acc+bias (either may be null)
// mode 1: outB = bf16( sigmoid(acc+bias) * HinF[row,col] )
__global__ __launch_bounds__(256) void gemm_b(
    const unsigned short* __restrict__ U, int K1,
    const unsigned short* __restrict__ V, int K2,
    const unsigned short* __restrict__ Wc, const float* __restrict__ bias,
    float* __restrict__ outF, unsigned short* __restrict__ outB,
    const float* __restrict__ HinF,
    int rows, int Mo, int mode)
{
    __shared__ __align__(16) unsigned short As[4][128][8];
    __shared__ __align__(16) unsigned short Bs[4][64][8];
    const int tid = threadIdx.x;
    const int row0 = blockIdx.y * 128;
    const int col0 = blockIdx.x * 64;
    const int K = K1 + K2;
    const int l = tid & 63, w = tid >> 6;
    const int lm = l & 15, lg = l >> 4;
    f32x4 acc[2][4] = {};

    for (int k0 = 0; k0 < K; k0 += 32) {
#pragma unroll
        for (int i = 0; i < 2; ++i) {
            int c = i * 256 + tid;
            int m = c & 127, g = c >> 7;          // g wave-uniform
            int row = row0 + m; if (row >= rows) row = rows - 1;
            int k = k0 + g * 8;
            const unsigned short* sp = (k < K1) ? U + (long)row * K1 + k
                                                : V + (long)row * K2 + (k - K1);
            gll16(sp, &As[0][0][0] + (((i * 256) + (w * 64)) << 3));
        }
        {
            const unsigned short* wp = Wc + ((long)((k0 >> 3) + w) * Mo + (col0 + l)) * 8;
            gll16(wp, &Bs[0][0][0] + ((w * 64) << 3));
        }
        __syncthreads();
        short8 a[2], b[4];
#pragma unroll
        for (int mi = 0; mi < 2; ++mi)
            a[mi] = *(const short8*)&As[lg][w * 32 + mi * 16 + lm][0];
#pragma unroll
        for (int ni = 0; ni < 4; ++ni)
            b[ni] = *(const short8*)&Bs[lg][ni * 16 + lm][0];
#pragma unroll
        for (int mi = 0; mi < 2; ++mi)
#pragma unroll
            for (int ni = 0; ni < 4; ++ni)
                acc[mi][ni] = __builtin_amdgcn_mfma_f32_16x16x32_bf16(a[mi], b[ni], acc[mi][ni], 0, 0, 0);
        __syncthreads();
    }
#pragma unroll
    for (int mi = 0; mi < 2; ++mi) {
        int rbase = row0 + w * 32 + mi * 16 + lg * 4;
#pragma unroll
        for (int r = 0; r < 4; ++r) {
            int row = rbase + r;
            if (row >= rows) continue;
#pragma unroll
            for (int ni = 0; ni < 4; ++ni) {
                int col = col0 + ni * 16 + lm;
                float v = acc[mi][ni][r] + (bias ? bias[col] : 0.f);
                if (mode == 1) {
                    float rr = 1.f / (1.f + __expf(-v));
                    outB[(long)row * Mo + col] = f2bf(rr * HinF[(long)row * Mo + col]);
                } else {
                    if (outF) outF[(long)row * Mo + col] = v;
                    if (outB) outB[(long)row * Mo + col] = f2bf(v);
                }
            }
        }
    }
}

// ================= bf16 MFMA fused GRU (phase-split, global_load_lds) ==========
__global__ __launch_bounds__(256) void gru_b(
    const unsigned short* __restrict__ Gb, const unsigned short* __restrict__ Hb,
    const unsigned short* __restrict__ RHb, const float* __restrict__ HinF, int D,
    const unsigned short* __restrict__ Wzc, const float* __restrict__ bz,
    const unsigned short* __restrict__ Whc, const float* __restrict__ bh,
    float* __restrict__ outF, unsigned short* __restrict__ outB, int rows)
{
    __shared__ __align__(16) unsigned short As0[4][128][8];
    __shared__ __align__(16) unsigned short As1[4][128][8];
    __shared__ __align__(16) unsigned short Bsz[4][64][8];
    __shared__ __align__(16) unsigned short Bsh[4][64][8];
    const int tid = threadIdx.x;
    const int row0 = blockIdx.y * 128;
    const int col0 = blockIdx.x * 64;
    const int l = tid & 63, w = tid >> 6;
    const int lm = l & 15, lg = l >> 4;
    f32x4 accz[2][4] = {}, acch[2][4] = {};

    // -------- phase 1: k in [0,D), A = G (shared by z and h) --------
    for (int k0 = 0; k0 < D; k0 += 32) {
#pragma unroll
        for (int i = 0; i < 2; ++i) {
            int c = i * 256 + tid;
            int m = c & 127, g = c >> 7;
            int row = row0 + m; if (row >= rows) row = rows - 1;
            gll16(Gb + (long)row * D + k0 + g * 8,
                  &As0[0][0][0] + (((i * 256) + (w * 64)) << 3));
        }
        {
            long base = ((long)((k0 >> 3) + w) * D + (col0 + l)) * 8;
            gll16(Wzc + base, &Bsz[0][0][0] + ((w * 64) << 3));
            gll16(Whc + base, &Bsh[0][0][0] + ((w * 64) << 3));
        }
        __syncthreads();
        short8 a[2], bzv[4], bhv[4];
#pragma unroll
        for (int mi = 0; mi < 2; ++mi)
            a[mi] = *(const short8*)&As0[lg][w * 32 + mi * 16 + lm][0];
#pragma unroll
        for (int ni = 0; ni < 4; ++ni) {
            bzv[ni] = *(const short8*)&Bsz[lg][ni * 16 + lm][0];
            bhv[ni] = *(const short8*)&Bsh[lg][ni * 16 + lm][0];
        }
#pragma unroll
        for (int mi = 0; mi < 2; ++mi)
#pragma unroll
            for (int ni = 0; ni < 4; ++ni) {
                accz[mi][ni] = __builtin_amdgcn_mfma_f32_16x16x32_bf16(a[mi], bzv[ni], accz[mi][ni], 0, 0, 0);
                acch[mi][ni] = __builtin_amdgcn_mfma_f32_16x16x32_bf16(a[mi], bhv[ni], acch[mi][ni], 0, 0, 0);
            }
        __syncthreads();
    }
    // -------- phase 2: k in [D,2D), Az = Hin, Ah = R*Hin --------
    for (int k0 = 0; k0 < D; k0 += 32) {
#pragma unroll
        for (int i = 0; i < 2; ++i) {
            int c = i * 256 + tid;
            int m = c & 127, g = c >> 7;
            int row = row0 + m; if (row >= rows) row = rows - 1;
            long off = (long)row * D + k0 + g * 8;
            gll16(Hb  + off, &As0[0][0][0] + (((i * 256) + (w * 64)) << 3));
            gll16(RHb + off, &As1[0][0][0] + (((i * 256) + (w * 64)) << 3));
        }
        {
            long base = ((long)(((D + k0) >> 3) + w) * D + (col0 + l)) * 8;
            gll16(Wzc + base, &Bsz[0][0][0] + ((w * 64) << 3));
            gll16(Whc + base, &Bsh[0][0][0] + ((w * 64) << 3));
        }
        __syncthreads();
        short8 az[2], ah[2], bzv[4], bhv[4];
#pragma unroll
        for (int mi = 0; mi < 2; ++mi) {
            az[mi] = *(const short8*)&As0[lg][w * 32 + mi * 16 + lm][0];
            ah[mi] = *(const short8*)&As1[lg][w * 32 + mi * 16 + lm][0];
        }
#pragma unroll
        for (int ni = 0; ni < 4; ++ni) {
            bzv[ni] = *(const short8*)&Bsz[lg][ni * 16 + lm][0];
            bhv[ni] = *(const short8*)&Bsh[lg][ni * 16 + lm][0];
        }
#pragma unroll
        for (int mi = 0; mi < 2; ++mi)
#pragma unroll
            for (int ni = 0; ni < 4; ++ni) {
                accz[mi][ni] = __builtin_amdgcn_mfma_f32_16x16x32_bf16(az[mi], bzv[ni], accz[mi][ni], 0, 0, 0);
                acch[mi][ni] = __builtin_amdgcn_mfma_f32_16x16x32_bf16(ah[mi], bhv[ni], acch[mi][ni], 0, 0, 0);
            }
        __syncthreads();
    }
#pragma unroll
    for (int mi = 0; mi < 2; ++mi) {
        int rbase = row0 + w * 32 + mi * 16 + lg * 4;
#pragma unroll
        for (int r = 0; r < 4; ++r) {
            int row = rbase + r;
            if (row >= rows) continue;
#pragma unroll
            for (int ni = 0; ni < 4; ++ni) {
                int col = col0 + ni * 16 + lm;
                float z  = 1.f / (1.f + __expf(-(accz[mi][ni][r] + bz[col])));
                float hh = tanhf(acch[mi][ni][r] + bh[col]);
                float hv = HinF[(long)row * D + col];
                float o  = (1.f - z) * hv + z * hh;
                if (outF) outF[(long)row * D + col] = o;
                if (outB) outB[(long)row * D + col] = f2bf(o);
            }
        }
    }
}

// ================= fp32 tiled SGEMM (layer-3) =================
__global__ __launch_bounds__(256) void gemm_k(
    const float* __restrict__ U, int K1,
    const float* __restrict__ V, int K2,
    const float* __restrict__ W, const float* __restrict__ bias,
    float* __restrict__ Cout, int rows, int Mo, int act)
{
    __shared__ float As[16][65];
    __shared__ float Bs[16][64];
    const int tid = threadIdx.x;
    const int row0 = blockIdx.y * 64;
    const int col0 = blockIdx.x * 64;
    const int tx = tid & 15, ty = tid >> 4;
    const int K = K1 + K2;
    float acc[4][4] = {};
    for (int k0 = 0; k0 < K; k0 += 16) {
#pragma unroll
        for (int i = 0; i < 4; ++i) {
            int idx = tid + i * 256;
            int rl = idx >> 4, kl = idx & 15;
            int r = row0 + rl, k = k0 + kl;
            float v = 0.f;
            if (r < rows) {
                if (k < K1) v = U[(long)r * K1 + k];
                else        v = V[(long)r * K2 + (k - K1)];
            }
            As[kl][rl] = v;
        }
#pragma unroll
        for (int i = 0; i < 4; ++i) {
            int idx = tid + i * 256;
            int kl = idx >> 6, jl = idx & 63;
            Bs[kl][jl] = W[(long)(k0 + kl) * Mo + (col0 + jl)];
        }
        __syncthreads();
#pragma unroll
        for (int k = 0; k < 16; ++k) {
            float a[4], b[4];
#pragma unroll
            for (int i = 0; i < 4; ++i) a[i] = As[k][ty * 4 + i];
#pragma unroll
            for (int j = 0; j < 4; ++j) b[j] = Bs[k][tx * 4 + j];
#pragma unroll
            for (int i = 0; i < 4; ++i)
#pragma unroll
                for (int j = 0; j < 4; ++j)
                    acc[i][j] += a[i] * b[j];
        }
        __syncthreads();
    }
#pragma unroll
    for (int i = 0; i < 4; ++i) {
        int r = row0 + ty * 4 + i;
        if (r >= rows) continue;
#pragma unroll
        for (int j = 0; j < 4; ++j) {
            int c = col0 + tx * 4 + j;
            float v = acc[i][j] + (bias ? bias[c] : 0.f);
            if (act == 1) v = 1.f / (1.f + __expf(-v));
            Cout[(long)r * Mo + c] = v;
        }
    }
}

// ---------------- fp32 fused GRU (layer 3) ----------------
__global__ __launch_bounds__(256) void gru_fused_k(
    const float* __restrict__ Gp, const float* __restrict__ Hin,
    const float* __restrict__ Rp, int D,
    const float* __restrict__ Wz, const float* __restrict__ bz,
    const float* __restrict__ Wh, const float* __restrict__ bh,
    float* __restrict__ Out, int rows)
{
    __shared__ float Az[16][65];
    __shared__ float Ah[16][65];
    __shared__ float Bz[16][64];
    __shared__ float Bh[16][64];
    const int tid = threadIdx.x;
    const int row0 = blockIdx.y * 64;
    const int col0 = blockIdx.x * 64;
    const int tx = tid & 15, ty = tid >> 4;
    const int K = 2 * D;
    float accz[4][4] = {}, acch[4][4] = {};
    for (int k0 = 0; k0 < K; k0 += 16) {
#pragma unroll
        for (int i = 0; i < 4; ++i) {
            int idx = tid + i * 256;
            int rl = idx >> 4, kl = idx & 15;
            int r = row0 + rl, k = k0 + kl;
            float vz = 0.f, vh = 0.f;
            if (r < rows) {
                if (k < D) { vz = Gp[(long)r * D + k]; vh = vz; }
                else {
                    int k2 = k - D;
                    float hv = Hin[(long)r * D + k2];
                    vz = hv; vh = hv * Rp[(long)r * D + k2];
                }
            }
            Az[kl][rl] = vz; Ah[kl][rl] = vh;
        }
#pragma unroll
        for (int i = 0; i < 4; ++i) {
            int idx = tid + i * 256;
            int kl = idx >> 6, jl = idx & 63;
            Bz[kl][jl] = Wz[(long)(k0 + kl) * D + (col0 + jl)];
            Bh[kl][jl] = Wh[(long)(k0 + kl) * D + (col0 + jl)];
        }
        __syncthreads();
#pragma unroll
        for (int k = 0; k < 16; ++k) {
            float az[4], ah[4], bzv[4], bhv[4];
#pragma unroll
            for (int i = 0; i < 4; ++i) { az[i] = Az[k][ty * 4 + i]; ah[i] = Ah[k][ty * 4 + i]; }
#pragma unroll
            for (int j = 0; j < 4; ++j) { bzv[j] = Bz[k][tx * 4 + j]; bhv[j] = Bh[k][tx * 4 + j]; }
#pragma unroll
            for (int i = 0; i < 4; ++i)
#pragma unroll
                for (int j = 0; j < 4; ++j) {
                    accz[i][j] += az[i] * bzv[j];
                    acch[i][j] += ah[i] * bhv[j];
                }
        }
        __syncthreads();
    }
#pragma unroll
    for (int i = 0; i < 4; ++i) {
        int r = row0 + ty * 4 + i;
        if (r >= rows) continue;
#pragma unroll
        for (int j = 0; j < 4; ++j) {
            int c = col0 + tx * 4 + j;
            float z = 1.f / (1.f + __expf(-(accz[i][j] + bz[c])));
            float hh = tanhf(acch[i][j] + bh[c]);
            float hv = Hin[(long)r * D + c];
            Out[(long)r * D + c] = (1.f - z) * hv + z * hh;
        }
    }
}

// ---------------- alpha (bf16 / fp32 inputs) ----------------
__global__ void alpha_b(const unsigned short* __restrict__ XPb,
                        const float* __restrict__ a_s, const float* __restrict__ a_d,
                        float* __restrict__ AS, float* __restrict__ AD,
                        int Nn, int H, int C)
{
    int i = blockIdx.x * blockDim.x + threadIdx.x;
    if (i >= Nn * H) return;
    int n = i / H, h = i % H;
    const unsigned short* xp = &XPb[(long)n * H * C + (long)h * C];
    float ss = 0.f, sd = 0.f;
    for (int c = 0; c < C; ++c) {
        float v = bf2f(xp[c]);
        ss += v * a_s[h * C + c];
        sd += v * a_d[h * C + c];
    }
    AS[i] = ss; AD[i] = sd;
}

__global__ void alpha_k(const float* __restrict__ XP,
                        const float* __restrict__ a_s, const float* __restrict__ a_d,
                        float* __restrict__ AS, float* __restrict__ AD,
                        int Nn, int H, int C)
{
    int i = blockIdx.x * blockDim.x + threadIdx.x;
    if (i >= Nn * H) return;
    int n = i / H, h = i % H;
    const float* xp = &XP[(long)n * H * C + (long)h * C];
    float ss = 0.f, sd = 0.f;
    for (int c = 0; c < C; ++c) {
        float v = xp[c];
        ss += v * a_s[h * C + c];
        sd += v * a_d[h * C + c];
    }
    AS[i] = ss; AD[i] = sd;
}

// ---------------- CSR build ----------------
__global__ void count_k(const int* __restrict__ dst, int E, int* __restrict__ cnt)
{
    int e = blockIdx.x * blockDim.x + threadIdx.x;
    if (e < E) atomicAdd(&cnt[dst[e]], 1);
}

__global__ __launch_bounds__(1024) void scan_k(const int* __restrict__ cnt, int Nn,
                                               int* __restrict__ off)
{
    __shared__ int part[1024];
    int tid = threadIdx.x;
    int chunk = (Nn + 1023) / 1024;
    int b = tid * chunk;
    int e = b + chunk; if (e > Nn) e = Nn; if (b > Nn) b = Nn;
    int s = 0;
    for (int i = b; i < e; ++i) s += cnt[i];
    part[tid] = s;
    __syncthreads();
    for (int d = 1; d < 1024; d <<= 1) {
        int v = (tid >= d) ? part[tid - d] : 0;
        __syncthreads();
        part[tid] += v;
        __syncthreads();
    }
    int run = tid ? part[tid - 1] : 0;
    for (int i = b; i < e; ++i) { off[i] = run; run += cnt[i]; }
    if (tid == 1023) off[Nn] = part[1023];
}

__global__ void scatter_k(const int* __restrict__ src, const int* __restrict__ dst, int E,
                          const int* __restrict__ off, int* __restrict__ cur,
                          int* __restrict__ csr_src)
{
    int e = blockIdx.x * blockDim.x + threadIdx.x;
    if (e < E) {
        int d = dst[e];
        int p = atomicAdd(&cur[d], 1);
        csr_src[off[d] + p] = src[e];
    }
}

// ---------------- bf16 GAT gather (8 feats/lane) ----------------
__global__ void gat_gather_b(const int* __restrict__ off, const int* __restrict__ csr_src,
                             const unsigned short* __restrict__ XPb,
                             const float* __restrict__ AS, const float* __restrict__ AD,
                             const float* __restrict__ bias,
                             unsigned short* __restrict__ Gout,
                             int Nn, int H, int C, int do_elu)
{
    const int D = H * C;
    const int lpn = D >> 3;
    const int npw = 64 / lpn;
    int lane = threadIdx.x & 63;
    long wave = ((long)blockIdx.x * blockDim.x + threadIdx.x) >> 6;
    int sub = lane / lpn;
    int cl = lane % lpn;
    long n = wave * npw + sub;
    if (n >= Nn) return;
    int j = cl * 8;
    int h = j / C;
    float ad = AD[n * H + h];
    float v = AS[n * H + h] + ad;
    v = v > 0.f ? v : NEG_SLOPE * v;
    float w = __expf(v);
    float den = w;
    float acc[8];
    {
        ushort8 xv = *(const ushort8*)&XPb[(long)n * D + j];
#pragma unroll
        for (int q = 0; q < 8; ++q) acc[q] = w * bf2f(xv[q]);
    }
    int b0 = off[n], b1 = off[n + 1];
    for (int i = b0; i < b1; ++i) {
        int s = csr_src[i];
        v = AS[s * H + h] + ad;
        v = v > 0.f ? v : NEG_SLOPE * v;
        w = __expf(v);
        den += w;
        ushort8 xv = *(const ushort8*)&XPb[(long)s * D + j];
#pragma unroll
        for (int q = 0; q < 8; ++q) acc[q] += w * bf2f(xv[q]);
    }
    float inv = 1.f / (den + 1e-16f);
    ushort8 ov;
#pragma unroll
    for (int q = 0; q < 8; ++q) {
        float o = acc[q] * inv + bias[j + q];
        if (do_elu) o = o > 0.f ? o : expm1f(o);
        ov[q] = f2bf(o);
    }
    *(ushort8*)&Gout[(long)n * D + j] = ov;
}

// ---------------- fp32 GAT gather (layer 3) ----------------
__global__ void gat_gather(const int* __restrict__ off, const int* __restrict__ csr_src,
                           const float* __restrict__ XP,
                           const float* __restrict__ AS, const float* __restrict__ AD,
                           const float* __restrict__ bias,
                           float* __restrict__ Gout, int Nn, int H, int C, int do_elu)
{
    const int D = H * C;
    const int lpn = D >> 2;
    const int npw = 64 / lpn;
    int lane = threadIdx.x & 63;
    long wave = ((long)blockIdx.x * blockDim.x + threadIdx.x) >> 6;
    int sub = lane / lpn;
    int cl = lane % lpn;
    long n = wave * npw + sub;
    if (n >= Nn) return;
    int j = cl * 4;
    int h = j / C;
    float ad = AD[n * H + h];
    float v = AS[n * H + h] + ad;
    v = v > 0.f ? v : NEG_SLOPE * v;
    float w = __expf(v);
    float den = w;
    float4 xv = *(const float4*)&XP[(long)n * D + j];
    float4 acc;
    acc.x = w * xv.x; acc.y = w * xv.y; acc.z = w * xv.z; acc.w = w * xv.w;
    int b0 = off[n], b1 = off[n + 1];
    for (int i = b0; i < b1; ++i) {
        int s = csr_src[i];
        v = AS[s * H + h] + ad;
        v = v > 0.f ? v : NEG_SLOPE * v;
        w = __expf(v);
        den += w;
        xv = *(const float4*)&XP[(long)s * D + j];
        acc.x += w * xv.x; acc.y += w * xv.y; acc.z += w * xv.z; acc.w += w * xv.w;
    }
    float inv = 1.f / (den + 1e-16f);
    float4 bv = *(const float4*)&bias[j];
    float o0 = acc.x * inv + bv.x;
    float o1 = acc.y * inv + bv.y;
    float o2 = acc.z * inv + bv.z;
    float o3 = acc.w * inv + bv.w;
    if (do_elu) {
        o0 = o0 > 0.f ? o0 : expm1f(o0);
        o1 = o1 > 0.f ? o1 : expm1f(o1);
        o2 = o2 > 0.f ? o2 : expm1f(o2);
        o3 = o3 > 0.f ? o3 : expm1f(o3);
    }
    float4 ov; ov.x = o0; ov.y = o1; ov.z = o2; ov.w = o3;
    *(float4*)&Gout[(long)n * D + j] = ov;
}

extern "C" void kernel_launch(void* const* d_in, const int* in_sizes, int n_in,
                              void* d_out, int out_size, void* d_ws, size_t ws_size,
                              hipStream_t stream)
{
    const float* x    = (const float*)d_in[0];
    const int*   ei   = (const int*)  d_in[1];
    const float* W_tr = (const float*)d_in[2];
    const float* b_tr = (const float*)d_in[3];
    const float* W1   = (const float*)d_in[4];
    const float* as1  = (const float*)d_in[5];
    const float* ad1  = (const float*)d_in[6];
    const float* b1   = (const float*)d_in[7];
    const float* Wr1  = (const float*)d_in[8];
    const float* br1  = (const float*)d_in[9];
    const float* Wz1  = (const float*)d_in[10];
    const float* bz1  = (const float*)d_in[11];
    const float* Wh1  = (const float*)d_in[12];
    const float* bh1  = (const float*)d_in[13];
    const float* Wp2  = (const float*)d_in[14];
    const float* bp2  = (const float*)d_in[15];
    const float* W2   = (const float*)d_in[16];
    const float* as2  = (const float*)d_in[17];
    const float* ad2  = (const float*)d_in[18];
    const float* b2   = (const float*)d_in[19];
    const float* Wr2  = (const float*)d_in[20];
    const float* br2  = (const float*)d_in[21];
    const float* Wz2  = (const float*)d_in[22];
    const float* bz2  = (const float*)d_in[23];
    const float* Wh2  = (const float*)d_in[24];
    const float* bh2  = (const float*)d_in[25];
    const float* Wp3  = (const float*)d_in[26];
    const float* bp3  = (const float*)d_in[27];
    const float* W3   = (const float*)d_in[28];
    const float* as3  = (const float*)d_in[29];
    const float* ad3  = (const float*)d_in[30];
    const float* b3   = (const float*)d_in[31];
    const float* Wr3  = (const float*)d_in[32];
    const float* br3  = (const float*)d_in[33];
    const float* Wz3  = (const float*)d_in[34];
    const float* bz3  = (const float*)d_in[35];
    const float* Wh3  = (const float*)d_in[36];
    const float* bh3  = (const float*)d_in[37];

    const int Nn = in_sizes[0] / 128;   // 50000
    const int E  = in_sizes[1] / 2;     // 800000
    const int* srcp = ei;
    const int* dstp = ei + E;

    // ---------------- workspace layout ----------------
    float* X0f  = (float*)d_ws;                         // [N,256] (layer3 reuses as 4x[N,64])
    float* HINf = X0f  + (size_t)Nn * 256;              // [N,128]
    float* CX2f = HINf + (size_t)Nn * 128;              // [N,128]
    float* AS   = CX2f + (size_t)Nn * 128;              // [N,8]
    float* AD   = AS   + (size_t)Nn * 8;                // [N,8]
    unsigned short* X0b  = (unsigned short*)(AD + (size_t)Nn * 8); // [N,256]
    unsigned short* XPb  = X0b + (size_t)Nn * 256;      // [N,256]
    unsigned short* Gb   = XPb + (size_t)Nn * 256;      // [N,256]
    unsigned short* RHb  = Gb  + (size_t)Nn * 256;      // [N,256]
    unsigned short* HINb = RHb + (size_t)Nn * 256;      // [N,128]
    unsigned short* wpool = HINb + (size_t)Nn * 128;
    unsigned short* Wtrc = wpool;                       // 128*256
    unsigned short* W1c  = Wtrc + 128 * 256;            // 256*256
    unsigned short* Wr1c = W1c  + 256 * 256;            // 512*256
    unsigned short* Wz1c = Wr1c + 512 * 256;
    unsigned short* Wh1c = Wz1c + 512 * 256;
    unsigned short* Wp2c = Wh1c + 512 * 256;            // 256*128
    unsigned short* W2c  = Wp2c + 256 * 128;
    unsigned short* Wr2c = W2c  + 256 * 128;
    unsigned short* Wz2c = Wr2c + 256 * 128;
    unsigned short* Wh2c = Wz2c + 256 * 128;
    int* ioff = (int*)(((size_t)(Wh2c + 256 * 128) + 15) & ~(size_t)15);
    int* cnt  = ioff + (Nn + 1);
    int* cur  = cnt + Nn;
    int* csr  = cur + Nn;

    dim3 blk(256);
    int rb  = (Nn + 63) / 64;
    int rbm = (Nn + 127) / 128;

    // ---------- all weight conversions in ONE launch ----------
    {
        WPack p;
        const float* Ws[10]      = {W_tr, W1, Wr1, Wz1, Wh1, Wp2, W2, Wr2, Wz2, Wh2};
        unsigned short* Wcs[10]  = {Wtrc, W1c, Wr1c, Wz1c, Wh1c, Wp2c, W2c, Wr2c, Wz2c, Wh2c};
        int Ks[10]               = {128, 256, 512, 512, 512, 256, 256, 256, 256, 256};
        int Mos[10]              = {256, 256, 256, 256, 256, 128, 128, 128, 128, 128};
        for (int i = 0; i < 10; ++i) { p.W[i] = Ws[i]; p.Wc[i] = Wcs[i]; p.K[i] = Ks[i]; p.Mo[i] = Mos[i]; }
        convW_all<<<dim3((512 * 256 + 255) / 256, 10), blk, 0, stream>>>(p);
    }

    // ---------- CSR build ----------
    hipMemsetAsync(cnt, 0, (size_t)Nn * 4, stream);
    hipMemsetAsync(cur, 0, (size_t)Nn * 4, stream);
    count_k<<<(E + 255) / 256, blk, 0, stream>>>(dstp, E, cnt);
    scan_k<<<1, 1024, 0, stream>>>(cnt, Nn, ioff);
    scatter_k<<<(E + 255) / 256, blk, 0, stream>>>(srcp, dstp, E, ioff, cur, csr);

    // ---------- stage 0 ----------
    unsigned short* xb = Gb;   // Gb free until gather1
    conv_k<<<(int)(((long)Nn * 128 / 4 + 255) / 256), blk, 0, stream>>>(x, xb, (long)Nn * 128);
    gemm_b<<<dim3(4, rbm), blk, 0, stream>>>(xb, 128, nullptr, 0, Wtrc, b_tr, X0f, X0b, nullptr, Nn, 256, 0);

    // ================= layer 1 (D=256, H=8, C=32) =================
    gemm_b<<<dim3(4, rbm), blk, 0, stream>>>(X0b, 256, nullptr, 0, W1c, nullptr, nullptr, XPb, nullptr, Nn, 256, 0);
    alpha_b<<<(Nn * 8 + 255) / 256, blk, 0, stream>>>(XPb, as1, ad1, AS, AD, Nn, 8, 32);
    {
        long waves = (Nn + 1) / 2;  // npw=2
        gat_gather_b<<<(int)((waves * 64 + 255) / 256), blk, 0, stream>>>(ioff, csr, XPb, AS, AD, b1, Gb, Nn, 8, 32, 1);
    }
    gemm_b<<<dim3(4, rbm), blk, 0, stream>>>(Gb, 256, X0b, 256, Wr1c, br1, nullptr, RHb, X0f, Nn, 256, 1);
    gru_b<<<dim3(4, rbm), blk, 0, stream>>>(Gb, X0b, RHb, X0f, 256, Wz1c, bz1, Wh1c, bh1, nullptr, XPb, Nn);
    // XPb holds x1 (bf16)

    // ================= layer 2 (D=128) =================
    gemm_b<<<dim3(2, rbm), blk, 0, stream>>>(XPb, 256, nullptr, 0, Wp2c, bp2, HINf, HINb, nullptr, Nn, 128, 0);
    gemm_b<<<dim3(2, rbm), blk, 0, stream>>>(XPb, 256, nullptr, 0, W2c, nullptr, nullptr, X0b, nullptr, Nn, 128, 0);
    alpha_b<<<(Nn * 4 + 255) / 256, blk, 0, stream>>>(X0b, as2, ad2, AS, AD, Nn, 4, 32);
    {
        long waves = (Nn + 3) / 4;  // npw=4
        gat_gather_b<<<(int)((waves * 64 + 255) / 256), blk, 0, stream>>>(ioff, csr, X0b, AS, AD, b2, Gb, Nn, 4, 32, 1);
    }
    gemm_b<<<dim3(2, rbm), blk, 0, stream>>>(Gb, 128, HINb, 128, Wr2c, br2, nullptr, RHb, HINf, Nn, 128, 1);
    gru_b<<<dim3(2, rbm), blk, 0, stream>>>(Gb, HINb, RHb, HINf, 128, Wz2c, bz2, Wh2c, bh2, CX2f, nullptr, Nn);
    // CX2f holds x2 (fp32)

    // ================= layer 3 (fp32, D=64) =================
    float* H3  = X0f;
    float* XP3 = X0f + (size_t)Nn * 64;
    float* G3  = X0f + (size_t)Nn * 128;
    float* R3  = X0f + (size_t)Nn * 192;
    gemm_k<<<dim3(1, rb), blk, 0, stream>>>(CX2f, 128, nullptr, 0, Wp3, bp3, H3, Nn, 64, 0);
    gemm_k<<<dim3(1, rb), blk, 0, stream>>>(CX2f, 128, nullptr, 0, W3, nullptr, XP3, Nn, 64, 0);
    alpha_k<<<(Nn + 255) / 256, blk, 0, stream>>>(XP3, as3, ad3, AS, AD, Nn, 1, 64);
    {
        long waves = (Nn + 3) / 4;  // lpn=16, npw=4
        gat_gather<<<(int)((waves * 64 + 255) / 256), blk, 0, stream>>>(ioff, csr, XP3, AS, AD, b3, G3, Nn, 1, 64, 0);
    }
    gemm_k<<<dim3(1, rb), blk, 0, stream>>>(G3, 64, H3, 64, Wr3, br3, R3, Nn, 64, 1);
    gru_fused_k<<<dim3(1, rb), blk, 0, stream>>>(G3, H3, R3, 64, Wz3, bz3, Wh3, bh3, (float*)d_out, Nn);
}

// Round 6
// 917.831 us; speedup vs baseline: 7.9631x; 1.0396x over previous
//
#include <hip/hip_runtime.h>

#define NEG_SLOPE 0.2f

typedef __attribute__((ext_vector_type(8))) short short8;
typedef __attribute__((ext_vector_type(8))) unsigned short ushort8;
typedef __attribute__((ext_vector_type(4))) float f32x4;

__device__ __forceinline__ unsigned short f2bf(float f) {
    unsigned int u = __float_as_uint(f);
    u += 0x7fff + ((u >> 16) & 1);     // round-to-nearest-even
    return (unsigned short)(u >> 16);
}
__device__ __forceinline__ float bf2f(unsigned short s) {
    return __uint_as_float(((unsigned int)s) << 16);
}

// async global->LDS, 16B per lane; lds base must be wave-uniform
__device__ __forceinline__ void gll16(const void* g, void* l) {
    __builtin_amdgcn_global_load_lds(
        (const __attribute__((address_space(1))) void*)g,
        (__attribute__((address_space(3))) void*)l, 16, 0, 0);
}

// ---------------- converters ----------------
__global__ void conv_k(const float* __restrict__ in, unsigned short* __restrict__ out, long n)
{
    long i = ((long)blockIdx.x * blockDim.x + threadIdx.x) * 4;
    if (i >= n) return;
    float4 f = *(const float4*)&in[i];
    ushort4 o; o.x = f2bf(f.x); o.y = f2bf(f.y); o.z = f2bf(f.z); o.w = f2bf(f.w);
    *(ushort4*)&out[i] = o;
}

// all weights in one launch: W[K][Mo] fp32 -> Wc[(k>>3)*Mo + m][8] bf16
struct WPack {
    const float* W[10];
    unsigned short* Wc[10];
    int K[10];
    int Mo[10];
};
__global__ void convW_all(WPack p)
{
    int wi = blockIdx.y;
    int i = blockIdx.x * blockDim.x + threadIdx.x;
    int K = p.K[wi], Mo = p.Mo[wi];
    if (i >= K * Mo) return;
    int k = i / Mo, m = i % Mo;
    p.Wc[wi][((long)(k >> 3) * Mo + m) * 8 + (k & 7)] = f2bf(p.W[wi][i]);
}

// XCD-grouping remap: 1-D grid padded to multiple of 8; consecutive work items
// (which share A-row panels) land on the same XCD's L2.
__device__ __forceinline__ int xcd_work(int TOT) {
    int L = blockIdx.x;
    int per = (TOT + 7) >> 3;
    int wk = (L & 7) * per + (L >> 3);
    return (wk < TOT) ? wk : -1;
}

// ================= bf16 MFMA GEMM (BK=64, global_load_lds, XCD remap) =========
// A = [U | V] bf16 row-major; Wc swizzled bf16; BM=128 BN=64 BK=64, 4 waves.
// mode 0: outF/outB = acc+bias (either may be null)
// mode 1: outB = bf16( sigmoid(acc+bias) * HinF[row,col] )
__global__ __launch_bounds__(256) void gemm_b(
    const unsigned short* __restrict__ U, int K1,
    const unsigned short* __restrict__ V, int K2,
    const unsigned short* __restrict__ Wc, const float* __restrict__ bias,
    float* __restrict__ outF, unsigned short* __restrict__ outB,
    const float* __restrict__ HinF,
    int rows, int Mo, int mode)
{
    __shared__ __align__(16) unsigned short As[8][128][8];   // 16KB
    __shared__ __align__(16) unsigned short Bs[8][64][8];    //  8KB
    const int CB = Mo >> 6;
    const int RB = (rows + 127) >> 7;
    int wk = xcd_work(CB * RB);
    if (wk < 0) return;
    const int col0 = (wk % CB) * 64;
    const int row0 = (wk / CB) * 128;
    const int K = K1 + K2;
    const int tid = threadIdx.x;
    const int l = tid & 63, w = tid >> 6;
    const int lm = l & 15, lg = l >> 4;
    f32x4 acc[2][4] = {};

    for (int k0 = 0; k0 < K; k0 += 64) {
#pragma unroll
        for (int i = 0; i < 4; ++i) {
            int c = i * 256 + tid;
            int m = c & 127, g = c >> 7;          // g wave-uniform
            int row = row0 + m; if (row >= rows) row = rows - 1;
            int k = k0 + g * 8;
            const unsigned short* sp = (k < K1) ? U + (long)row * K1 + k
                                                : V + (long)row * K2 + (k - K1);
            gll16(sp, &As[0][0][0] + ((i * 256 + w * 64) << 3));
        }
#pragma unroll
        for (int j = 0; j < 2; ++j) {
            int c = j * 256 + tid;
            int n = c & 63, g = c >> 6;           // g wave-uniform
            gll16(Wc + ((long)((k0 >> 3) + g) * Mo + (col0 + n)) * 8,
                  &Bs[0][0][0] + ((j * 256 + w * 64) << 3));
        }
        __syncthreads();
#pragma unroll
        for (int kk = 0; kk < 2; ++kk) {
            short8 a[2], b[4];
#pragma unroll
            for (int mi = 0; mi < 2; ++mi)
                a[mi] = *(const short8*)&As[kk * 4 + lg][w * 32 + mi * 16 + lm][0];
#pragma unroll
            for (int ni = 0; ni < 4; ++ni)
                b[ni] = *(const short8*)&Bs[kk * 4 + lg][ni * 16 + lm][0];
#pragma unroll
            for (int mi = 0; mi < 2; ++mi)
#pragma unroll
                for (int ni = 0; ni < 4; ++ni)
                    acc[mi][ni] = __builtin_amdgcn_mfma_f32_16x16x32_bf16(a[mi], b[ni], acc[mi][ni], 0, 0, 0);
        }
        __syncthreads();
    }
#pragma unroll
    for (int mi = 0; mi < 2; ++mi) {
        int rbase = row0 + w * 32 + mi * 16 + lg * 4;
#pragma unroll
        for (int r = 0; r < 4; ++r) {
            int row = rbase + r;
            if (row >= rows) continue;
#pragma unroll
            for (int ni = 0; ni < 4; ++ni) {
                int col = col0 + ni * 16 + lm;
                float v = acc[mi][ni][r] + (bias ? bias[col] : 0.f);
                if (mode == 1) {
                    float rr = 1.f / (1.f + __expf(-v));
                    outB[(long)row * Mo + col] = f2bf(rr * HinF[(long)row * Mo + col]);
                } else {
                    if (outF) outF[(long)row * Mo + col] = v;
                    if (outB) outB[(long)row * Mo + col] = f2bf(v);
                }
            }
        }
    }
}

// ================= bf16 MFMA fused GRU (phase-split, BK=64) =================
__global__ __launch_bounds__(256) void gru_b(
    const unsigned short* __restrict__ Gb, const unsigned short* __restrict__ Hb,
    const unsigned short* __restrict__ RHb, const float* __restrict__ HinF, int D,
    const unsigned short* __restrict__ Wzc, const float* __restrict__ bz,
    const unsigned short* __restrict__ Whc, const float* __restrict__ bh,
    float* __restrict__ outF, unsigned short* __restrict__ outB, int rows)
{
    __shared__ __align__(16) unsigned short As0[8][128][8];  // 16KB
    __shared__ __align__(16) unsigned short As1[8][128][8];  // 16KB
    __shared__ __align__(16) unsigned short Bsz[8][64][8];   //  8KB
    __shared__ __align__(16) unsigned short Bsh[8][64][8];   //  8KB
    const int CB = D >> 6;
    const int RB = (rows + 127) >> 7;
    int wk = xcd_work(CB * RB);
    if (wk < 0) return;
    const int col0 = (wk % CB) * 64;
    const int row0 = (wk / CB) * 128;
    const int tid = threadIdx.x;
    const int l = tid & 63, w = tid >> 6;
    const int lm = l & 15, lg = l >> 4;
    f32x4 accz[2][4] = {}, acch[2][4] = {};

    // -------- phase 1: k in [0,D), A = G (shared by z and h) --------
    for (int k0 = 0; k0 < D; k0 += 64) {
#pragma unroll
        for (int i = 0; i < 4; ++i) {
            int c = i * 256 + tid;
            int m = c & 127, g = c >> 7;
            int row = row0 + m; if (row >= rows) row = rows - 1;
            gll16(Gb + (long)row * D + k0 + g * 8,
                  &As0[0][0][0] + ((i * 256 + w * 64) << 3));
        }
#pragma unroll
        for (int j = 0; j < 2; ++j) {
            int c = j * 256 + tid;
            int n = c & 63, g = c >> 6;
            long base = ((long)((k0 >> 3) + g) * D + (col0 + n)) * 8;
            gll16(Wzc + base, &Bsz[0][0][0] + ((j * 256 + w * 64) << 3));
            gll16(Whc + base, &Bsh[0][0][0] + ((j * 256 + w * 64) << 3));
        }
        __syncthreads();
#pragma unroll
        for (int kk = 0; kk < 2; ++kk) {
            short8 a[2], bzv[4], bhv[4];
#pragma unroll
            for (int mi = 0; mi < 2; ++mi)
                a[mi] = *(const short8*)&As0[kk * 4 + lg][w * 32 + mi * 16 + lm][0];
#pragma unroll
            for (int ni = 0; ni < 4; ++ni) {
                bzv[ni] = *(const short8*)&Bsz[kk * 4 + lg][ni * 16 + lm][0];
                bhv[ni] = *(const short8*)&Bsh[kk * 4 + lg][ni * 16 + lm][0];
            }
#pragma unroll
            for (int mi = 0; mi < 2; ++mi)
#pragma unroll
                for (int ni = 0; ni < 4; ++ni) {
                    accz[mi][ni] = __builtin_amdgcn_mfma_f32_16x16x32_bf16(a[mi], bzv[ni], accz[mi][ni], 0, 0, 0);
                    acch[mi][ni] = __builtin_amdgcn_mfma_f32_16x16x32_bf16(a[mi], bhv[ni], acch[mi][ni], 0, 0, 0);
                }
        }
        __syncthreads();
    }
    // -------- phase 2: k in [D,2D), Az = Hin, Ah = R*Hin --------
    for (int k0 = 0; k0 < D; k0 += 64) {
#pragma unroll
        for (int i = 0; i < 4; ++i) {
            int c = i * 256 + tid;
            int m = c & 127, g = c >> 7;
            int row = row0 + m; if (row >= rows) row = rows - 1;
            long off = (long)row * D + k0 + g * 8;
            gll16(Hb  + off, &As0[0][0][0] + ((i * 256 + w * 64) << 3));
            gll16(RHb + off, &As1[0][0][0] + ((i * 256 + w * 64) << 3));
        }
#pragma unroll
        for (int j = 0; j < 2; ++j) {
            int c = j * 256 + tid;
            int n = c & 63, g = c >> 6;
            long base = ((long)(((D + k0) >> 3) + g) * D + (col0 + n)) * 8;
            gll16(Wzc + base, &Bsz[0][0][0] + ((j * 256 + w * 64) << 3));
            gll16(Whc + base, &Bsh[0][0][0] + ((j * 256 + w * 64) << 3));
        }
        __syncthreads();
#pragma unroll
        for (int kk = 0; kk < 2; ++kk) {
            short8 az[2], ah[2], bzv[4], bhv[4];
#pragma unroll
            for (int mi = 0; mi < 2; ++mi) {
                az[mi] = *(const short8*)&As0[kk * 4 + lg][w * 32 + mi * 16 + lm][0];
                ah[mi] = *(const short8*)&As1[kk * 4 + lg][w * 32 + mi * 16 + lm][0];
            }
#pragma unroll
            for (int ni = 0; ni < 4; ++ni) {
                bzv[ni] = *(const short8*)&Bsz[kk * 4 + lg][ni * 16 + lm][0];
                bhv[ni] = *(const short8*)&Bsh[kk * 4 + lg][ni * 16 + lm][0];
            }
#pragma unroll
            for (int mi = 0; mi < 2; ++mi)
#pragma unroll
                for (int ni = 0; ni < 4; ++ni) {
                    accz[mi][ni] = __builtin_amdgcn_mfma_f32_16x16x32_bf16(az[mi], bzv[ni], accz[mi][ni], 0, 0, 0);
                    acch[mi][ni] = __builtin_amdgcn_mfma_f32_16x16x32_bf16(ah[mi], bhv[ni], acch[mi][ni], 0, 0, 0);
                }
        }
        __syncthreads();
    }
#pragma unroll
    for (int mi = 0; mi < 2; ++mi) {
        int rbase = row0 + w * 32 + mi * 16 + lg * 4;
#pragma unroll
        for (int r = 0; r < 4; ++r) {
            int row = rbase + r;
            if (row >= rows) continue;
#pragma unroll
            for (int ni = 0; ni < 4; ++ni) {
                int col = col0 + ni * 16 + lm;
                float z  = 1.f / (1.f + __expf(-(accz[mi][ni][r] + bz[col])));
                float hh = tanhf(acch[mi][ni][r] + bh[col]);
                float hv = HinF[(long)row * D + col];
                float o  = (1.f - z) * hv + z * hh;
                if (outF) outF[(long)row * D + col] = o;
                if (outB) outB[(long)row * D + col] = f2bf(o);
            }
        }
    }
}

// ================= fp32 tiled SGEMM (layer-3) =================
__global__ __launch_bounds__(256) void gemm_k(
    const float* __restrict__ U, int K1,
    const float* __restrict__ V, int K2,
    const float* __restrict__ W, const float* __restrict__ bias,
    float* __restrict__ Cout, int rows, int Mo, int act)
{
    __shared__ float As[16][65];
    __shared__ float Bs[16][64];
    const int tid = threadIdx.x;
    const int row0 = blockIdx.y * 64;
    const int col0 = blockIdx.x * 64;
    const int tx = tid & 15, ty = tid >> 4;
    const int K = K1 + K2;
    float acc[4][4] = {};
    for (int k0 = 0; k0 < K; k0 += 16) {
#pragma unroll
        for (int i = 0; i < 4; ++i) {
            int idx = tid + i * 256;
            int rl = idx >> 4, kl = idx & 15;
            int r = row0 + rl, k = k0 + kl;
            float v = 0.f;
            if (r < rows) {
                if (k < K1) v = U[(long)r * K1 + k];
                else        v = V[(long)r * K2 + (k - K1)];
            }
            As[kl][rl] = v;
        }
#pragma unroll
        for (int i = 0; i < 4; ++i) {
            int idx = tid + i * 256;
            int kl = idx >> 6, jl = idx & 63;
            Bs[kl][jl] = W[(long)(k0 + kl) * Mo + (col0 + jl)];
        }
        __syncthreads();
#pragma unroll
        for (int k = 0; k < 16; ++k) {
            float a[4], b[4];
#pragma unroll
            for (int i = 0; i < 4; ++i) a[i] = As[k][ty * 4 + i];
#pragma unroll
            for (int j = 0; j < 4; ++j) b[j] = Bs[k][tx * 4 + j];
#pragma unroll
            for (int i = 0; i < 4; ++i)
#pragma unroll
                for (int j = 0; j < 4; ++j)
                    acc[i][j] += a[i] * b[j];
        }
        __syncthreads();
    }
#pragma unroll
    for (int i = 0; i < 4; ++i) {
        int r = row0 + ty * 4 + i;
        if (r >= rows) continue;
#pragma unroll
        for (int j = 0; j < 4; ++j) {
            int c = col0 + tx * 4 + j;
            float v = acc[i][j] + (bias ? bias[c] : 0.f);
            if (act == 1) v = 1.f / (1.f + __expf(-v));
            Cout[(long)r * Mo + c] = v;
        }
    }
}

// ---------------- fp32 fused GRU (layer 3) ----------------
__global__ __launch_bounds__(256) void gru_fused_k(
    const float* __restrict__ Gp, const float* __restrict__ Hin,
    const float* __restrict__ Rp, int D,
    const float* __restrict__ Wz, const float* __restrict__ bz,
    const float* __restrict__ Wh, const float* __restrict__ bh,
    float* __restrict__ Out, int rows)
{
    __shared__ float Az[16][65];
    __shared__ float Ah[16][65];
    __shared__ float Bz[16][64];
    __shared__ float Bh[16][64];
    const int tid = threadIdx.x;
    const int row0 = blockIdx.y * 64;
    const int col0 = blockIdx.x * 64;
    const int tx = tid & 15, ty = tid >> 4;
    const int K = 2 * D;
    float accz[4][4] = {}, acch[4][4] = {};
    for (int k0 = 0; k0 < K; k0 += 16) {
#pragma unroll
        for (int i = 0; i < 4; ++i) {
            int idx = tid + i * 256;
            int rl = idx >> 4, kl = idx & 15;
            int r = row0 + rl, k = k0 + kl;
            float vz = 0.f, vh = 0.f;
            if (r < rows) {
                if (k < D) { vz = Gp[(long)r * D + k]; vh = vz; }
                else {
                    int k2 = k - D;
                    float hv = Hin[(long)r * D + k2];
                    vz = hv; vh = hv * Rp[(long)r * D + k2];
                }
            }
            Az[kl][rl] = vz; Ah[kl][rl] = vh;
        }
#pragma unroll
        for (int i = 0; i < 4; ++i) {
            int idx = tid + i * 256;
            int kl = idx >> 6, jl = idx & 63;
            Bz[kl][jl] = Wz[(long)(k0 + kl) * D + (col0 + jl)];
            Bh[kl][jl] = Wh[(long)(k0 + kl) * D + (col0 + jl)];
        }
        __syncthreads();
#pragma unroll
        for (int k = 0; k < 16; ++k) {
            float az[4], ah[4], bzv[4], bhv[4];
#pragma unroll
            for (int i = 0; i < 4; ++i) { az[i] = Az[k][ty * 4 + i]; ah[i] = Ah[k][ty * 4 + i]; }
#pragma unroll
            for (int j = 0; j < 4; ++j) { bzv[j] = Bz[k][tx * 4 + j]; bhv[j] = Bh[k][tx * 4 + j]; }
#pragma unroll
            for (int i = 0; i < 4; ++i)
#pragma unroll
                for (int j = 0; j < 4; ++j) {
                    accz[i][j] += az[i] * bzv[j];
                    acch[i][j] += ah[i] * bhv[j];
                }
        }
        __syncthreads();
    }
#pragma unroll
    for (int i = 0; i < 4; ++i) {
        int r = row0 + ty * 4 + i;
        if (r >= rows) continue;
#pragma unroll
        for (int j = 0; j < 4; ++j) {
            int c = col0 + tx * 4 + j;
            float z = 1.f / (1.f + __expf(-(accz[i][j] + bz[c])));
            float hh = tanhf(acch[i][j] + bh[c]);
            float hv = Hin[(long)r * D + c];
            Out[(long)r * D + c] = (1.f - z) * hv + z * hh;
        }
    }
}

// ---------------- alpha (bf16 / fp32 inputs) ----------------
__global__ void alpha_b(const unsigned short* __restrict__ XPb,
                        const float* __restrict__ a_s, const float* __restrict__ a_d,
                        float* __restrict__ AS, float* __restrict__ AD,
                        int Nn, int H, int C)
{
    int i = blockIdx.x * blockDim.x + threadIdx.x;
    if (i >= Nn * H) return;
    int n = i / H, h = i % H;
    const unsigned short* xp = &XPb[(long)n * H * C + (long)h * C];
    float ss = 0.f, sd = 0.f;
    for (int c = 0; c < C; ++c) {
        float v = bf2f(xp[c]);
        ss += v * a_s[h * C + c];
        sd += v * a_d[h * C + c];
    }
    AS[i] = ss; AD[i] = sd;
}

__global__ void alpha_k(const float* __restrict__ XP,
                        const float* __restrict__ a_s, const float* __restrict__ a_d,
                        float* __restrict__ AS, float* __restrict__ AD,
                        int Nn, int H, int C)
{
    int i = blockIdx.x * blockDim.x + threadIdx.x;
    if (i >= Nn * H) return;
    int n = i / H, h = i % H;
    const float* xp = &XP[(long)n * H * C + (long)h * C];
    float ss = 0.f, sd = 0.f;
    for (int c = 0; c < C; ++c) {
        float v = xp[c];
        ss += v * a_s[h * C + c];
        sd += v * a_d[h * C + c];
    }
    AS[i] = ss; AD[i] = sd;
}

// ---------------- CSR build ----------------
__global__ void count_k(const int* __restrict__ dst, int E, int* __restrict__ cnt)
{
    int e = blockIdx.x * blockDim.x + threadIdx.x;
    if (e < E) atomicAdd(&cnt[dst[e]], 1);
}

__global__ __launch_bounds__(1024) void scan_k(const int* __restrict__ cnt, int Nn,
                                               int* __restrict__ off)
{
    __shared__ int part[1024];
    int tid = threadIdx.x;
    int chunk = (Nn + 1023) / 1024;
    int b = tid * chunk;
    int e = b + chunk; if (e > Nn) e = Nn; if (b > Nn) b = Nn;
    int s = 0;
    for (int i = b; i < e; ++i) s += cnt[i];
    part[tid] = s;
    __syncthreads();
    for (int d = 1; d < 1024; d <<= 1) {
        int v = (tid >= d) ? part[tid - d] : 0;
        __syncthreads();
        part[tid] += v;
        __syncthreads();
    }
    int run = tid ? part[tid - 1] : 0;
    for (int i = b; i < e; ++i) { off[i] = run; run += cnt[i]; }
    if (tid == 1023) off[Nn] = part[1023];
}

__global__ void scatter_k(const int* __restrict__ src, const int* __restrict__ dst, int E,
                          const int* __restrict__ off, int* __restrict__ cur,
                          int* __restrict__ csr_src)
{
    int e = blockIdx.x * blockDim.x + threadIdx.x;
    if (e < E) {
        int d = dst[e];
        int p = atomicAdd(&cur[d], 1);
        csr_src[off[d] + p] = src[e];
    }
}

// ---------------- bf16 GAT gather (8 feats/lane) ----------------
__global__ void gat_gather_b(const int* __restrict__ off, const int* __restrict__ csr_src,
                             const unsigned short* __restrict__ XPb,
                             const float* __restrict__ AS, const float* __restrict__ AD,
                             const float* __restrict__ bias,
                             unsigned short* __restrict__ Gout,
                             int Nn, int H, int C, int do_elu)
{
    const int D = H * C;
    const int lpn = D >> 3;
    const int npw = 64 / lpn;
    int lane = threadIdx.x & 63;
    long wave = ((long)blockIdx.x * blockDim.x + threadIdx.x) >> 6;
    int sub = lane / lpn;
    int cl = lane % lpn;
    long n = wave * npw + sub;
    if (n >= Nn) return;
    int j = cl * 8;
    int h = j / C;
    float ad = AD[n * H + h];
    float v = AS[n * H + h] + ad;
    v = v > 0.f ? v : NEG_SLOPE * v;
    float w = __expf(v);
    float den = w;
    float acc[8];
    {
        ushort8 xv = *(const ushort8*)&XPb[(long)n * D + j];
#pragma unroll
        for (int q = 0; q < 8; ++q) acc[q] = w * bf2f(xv[q]);
    }
    int b0 = off[n], b1 = off[n + 1];
    for (int i = b0; i < b1; ++i) {
        int s = csr_src[i];
        v = AS[s * H + h] + ad;
        v = v > 0.f ? v : NEG_SLOPE * v;
        w = __expf(v);
        den += w;
        ushort8 xv = *(const ushort8*)&XPb[(long)s * D + j];
#pragma unroll
        for (int q = 0; q < 8; ++q) acc[q] += w * bf2f(xv[q]);
    }
    float inv = 1.f / (den + 1e-16f);
    ushort8 ov;
#pragma unroll
    for (int q = 0; q < 8; ++q) {
        float o = acc[q] * inv + bias[j + q];
        if (do_elu) o = o > 0.f ? o : expm1f(o);
        ov[q] = f2bf(o);
    }
    *(ushort8*)&Gout[(long)n * D + j] = ov;
}

// ---------------- fp32 GAT gather (layer 3) ----------------
__global__ void gat_gather(const int* __restrict__ off, const int* __restrict__ csr_src,
                           const float* __restrict__ XP,
                           const float* __restrict__ AS, const float* __restrict__ AD,
                           const float* __restrict__ bias,
                           float* __restrict__ Gout, int Nn, int H, int C, int do_elu)
{
    const int D = H * C;
    const int lpn = D >> 2;
    const int npw = 64 / lpn;
    int lane = threadIdx.x & 63;
    long wave = ((long)blockIdx.x * blockDim.x + threadIdx.x) >> 6;
    int sub = lane / lpn;
    int cl = lane % lpn;
    long n = wave * npw + sub;
    if (n >= Nn) return;
    int j = cl * 4;
    int h = j / C;
    float ad = AD[n * H + h];
    float v = AS[n * H + h] + ad;
    v = v > 0.f ? v : NEG_SLOPE * v;
    float w = __expf(v);
    float den = w;
    float4 xv = *(const float4*)&XP[(long)n * D + j];
    float4 acc;
    acc.x = w * xv.x; acc.y = w * xv.y; acc.z = w * xv.z; acc.w = w * xv.w;
    int b0 = off[n], b1 = off[n + 1];
    for (int i = b0; i < b1; ++i) {
        int s = csr_src[i];
        v = AS[s * H + h] + ad;
        v = v > 0.f ? v : NEG_SLOPE * v;
        w = __expf(v);
        den += w;
        xv = *(const float4*)&XP[(long)s * D + j];
        acc.x += w * xv.x; acc.y += w * xv.y; acc.z += w * xv.z; acc.w += w * xv.w;
    }
    float inv = 1.f / (den + 1e-16f);
    float4 bv = *(const float4*)&bias[j];
    float o0 = acc.x * inv + bv.x;
    float o1 = acc.y * inv + bv.y;
    float o2 = acc.z * inv + bv.z;
    float o3 = acc.w * inv + bv.w;
    if (do_elu) {
        o0 = o0 > 0.f ? o0 : expm1f(o0);
        o1 = o1 > 0.f ? o1 : expm1f(o1);
        o2 = o2 > 0.f ? o2 : expm1f(o2);
        o3 = o3 > 0.f ? o3 : expm1f(o3);
    }
    float4 ov; ov.x = o0; ov.y = o1; ov.z = o2; ov.w = o3;
    *(float4*)&Gout[(long)n * D + j] = ov;
}

static inline int mfma_blocks(int rows, int Mo) {
    int TOT = (Mo >> 6) * ((rows + 127) >> 7);
    return ((TOT + 7) / 8) * 8;
}

extern "C" void kernel_launch(void* const* d_in, const int* in_sizes, int n_in,
                              void* d_out, int out_size, void* d_ws, size_t ws_size,
                              hipStream_t stream)
{
    const float* x    = (const float*)d_in[0];
    const int*   ei   = (const int*)  d_in[1];
    const float* W_tr = (const float*)d_in[2];
    const float* b_tr = (const float*)d_in[3];
    const float* W1   = (const float*)d_in[4];
    const float* as1  = (const float*)d_in[5];
    const float* ad1  = (const float*)d_in[6];
    const float* b1   = (const float*)d_in[7];
    const float* Wr1  = (const float*)d_in[8];
    const float* br1  = (const float*)d_in[9];
    const float* Wz1  = (const float*)d_in[10];
    const float* bz1  = (const float*)d_in[11];
    const float* Wh1  = (const float*)d_in[12];
    const float* bh1  = (const float*)d_in[13];
    const float* Wp2  = (const float*)d_in[14];
    const float* bp2  = (const float*)d_in[15];
    const float* W2   = (const float*)d_in[16];
    const float* as2  = (const float*)d_in[17];
    const float* ad2  = (const float*)d_in[18];
    const float* b2   = (const float*)d_in[19];
    const float* Wr2  = (const float*)d_in[20];
    const float* br2  = (const float*)d_in[21];
    const float* Wz2  = (const float*)d_in[22];
    const float* bz2  = (const float*)d_in[23];
    const float* Wh2  = (const float*)d_in[24];
    const float* bh2  = (const float*)d_in[25];
    const float* Wp3  = (const float*)d_in[26];
    const float* bp3  = (const float*)d_in[27];
    const float* W3   = (const float*)d_in[28];
    const float* as3  = (const float*)d_in[29];
    const float* ad3  = (const float*)d_in[30];
    const float* b3   = (const float*)d_in[31];
    const float* Wr3  = (const float*)d_in[32];
    const float* br3  = (const float*)d_in[33];
    const float* Wz3  = (const float*)d_in[34];
    const float* bz3  = (const float*)d_in[35];
    const float* Wh3  = (const float*)d_in[36];
    const float* bh3  = (const float*)d_in[37];

    const int Nn = in_sizes[0] / 128;   // 50000
    const int E  = in_sizes[1] / 2;     // 800000
    const int* srcp = ei;
    const int* dstp = ei + E;

    // ---------------- workspace layout ----------------
    float* X0f  = (float*)d_ws;                         // [N,256] (layer3 reuses as 4x[N,64])
    float* HINf = X0f  + (size_t)Nn * 256;              // [N,128]
    float* CX2f = HINf + (size_t)Nn * 128;              // [N,128]
    float* AS   = CX2f + (size_t)Nn * 128;              // [N,8]
    float* AD   = AS   + (size_t)Nn * 8;                // [N,8]
    unsigned short* X0b  = (unsigned short*)(AD + (size_t)Nn * 8); // [N,256]
    unsigned short* XPb  = X0b + (size_t)Nn * 256;      // [N,256]
    unsigned short* Gb   = XPb + (size_t)Nn * 256;      // [N,256]
    unsigned short* RHb  = Gb  + (size_t)Nn * 256;      // [N,256]
    unsigned short* HINb = RHb + (size_t)Nn * 256;      // [N,128]
    unsigned short* wpool = HINb + (size_t)Nn * 128;
    unsigned short* Wtrc = wpool;                       // 128*256
    unsigned short* W1c  = Wtrc + 128 * 256;            // 256*256
    unsigned short* Wr1c = W1c  + 256 * 256;            // 512*256
    unsigned short* Wz1c = Wr1c + 512 * 256;
    unsigned short* Wh1c = Wz1c + 512 * 256;
    unsigned short* Wp2c = Wh1c + 512 * 256;            // 256*128
    unsigned short* W2c  = Wp2c + 256 * 128;
    unsigned short* Wr2c = W2c  + 256 * 128;
    unsigned short* Wz2c = Wr2c + 256 * 128;
    unsigned short* Wh2c = Wz2c + 256 * 128;
    int* ioff = (int*)(((size_t)(Wh2c + 256 * 128) + 15) & ~(size_t)15);
    int* cnt  = ioff + (Nn + 1);
    int* cur  = cnt + Nn;
    int* csr  = cur + Nn;

    dim3 blk(256);
    int rb  = (Nn + 63) / 64;

    // ---------- all weight conversions in ONE launch ----------
    {
        WPack p;
        const float* Ws[10]      = {W_tr, W1, Wr1, Wz1, Wh1, Wp2, W2, Wr2, Wz2, Wh2};
        unsigned short* Wcs[10]  = {Wtrc, W1c, Wr1c, Wz1c, Wh1c, Wp2c, W2c, Wr2c, Wz2c, Wh2c};
        int Ks[10]               = {128, 256, 512, 512, 512, 256, 256, 256, 256, 256};
        int Mos[10]              = {256, 256, 256, 256, 256, 128, 128, 128, 128, 128};
        for (int i = 0; i < 10; ++i) { p.W[i] = Ws[i]; p.Wc[i] = Wcs[i]; p.K[i] = Ks[i]; p.Mo[i] = Mos[i]; }
        convW_all<<<dim3((512 * 256 + 255) / 256, 10), blk, 0, stream>>>(p);
    }

    // ---------- CSR build ----------
    hipMemsetAsync(cnt, 0, (size_t)Nn * 4, stream);
    hipMemsetAsync(cur, 0, (size_t)Nn * 4, stream);
    count_k<<<(E + 255) / 256, blk, 0, stream>>>(dstp, E, cnt);
    scan_k<<<1, 1024, 0, stream>>>(cnt, Nn, ioff);
    scatter_k<<<(E + 255) / 256, blk, 0, stream>>>(srcp, dstp, E, ioff, cur, csr);

    // ---------- stage 0 ----------
    unsigned short* xb = Gb;   // Gb free until gather1
    conv_k<<<(int)(((long)Nn * 128 / 4 + 255) / 256), blk, 0, stream>>>(x, xb, (long)Nn * 128);
    gemm_b<<<mfma_blocks(Nn, 256), blk, 0, stream>>>(xb, 128, nullptr, 0, Wtrc, b_tr, X0f, X0b, nullptr, Nn, 256, 0);

    // ================= layer 1 (D=256, H=8, C=32) =================
    gemm_b<<<mfma_blocks(Nn, 256), blk, 0, stream>>>(X0b, 256, nullptr, 0, W1c, nullptr, nullptr, XPb, nullptr, Nn, 256, 0);
    alpha_b<<<(Nn * 8 + 255) / 256, blk, 0, stream>>>(XPb, as1, ad1, AS, AD, Nn, 8, 32);
    {
        long waves = (Nn + 1) / 2;  // npw=2
        gat_gather_b<<<(int)((waves * 64 + 255) / 256), blk, 0, stream>>>(ioff, csr, XPb, AS, AD, b1, Gb, Nn, 8, 32, 1);
    }
    gemm_b<<<mfma_blocks(Nn, 256), blk, 0, stream>>>(Gb, 256, X0b, 256, Wr1c, br1, nullptr, RHb, X0f, Nn, 256, 1);
    gru_b<<<mfma_blocks(Nn, 256), blk, 0, stream>>>(Gb, X0b, RHb, X0f, 256, Wz1c, bz1, Wh1c, bh1, nullptr, XPb, Nn);
    // XPb holds x1 (bf16)

    // ================= layer 2 (D=128) =================
    gemm_b<<<mfma_blocks(Nn, 128), blk, 0, stream>>>(XPb, 256, nullptr, 0, Wp2c, bp2, HINf, HINb, nullptr, Nn, 128, 0);
    gemm_b<<<mfma_blocks(Nn, 128), blk, 0, stream>>>(XPb, 256, nullptr, 0, W2c, nullptr, nullptr, X0b, nullptr, Nn, 128, 0);
    alpha_b<<<(Nn * 4 + 255) / 256, blk, 0, stream>>>(X0b, as2, ad2, AS, AD, Nn, 4, 32);
    {
        long waves = (Nn + 3) / 4;  // npw=4
        gat_gather_b<<<(int)((waves * 64 + 255) / 256), blk, 0, stream>>>(ioff, csr, X0b, AS, AD, b2, Gb, Nn, 4, 32, 1);
    }
    gemm_b<<<mfma_blocks(Nn, 128), blk, 0, stream>>>(Gb, 128, HINb, 128, Wr2c, br2, nullptr, RHb, HINf, Nn, 128, 1);
    gru_b<<<mfma_blocks(Nn, 128), blk, 0, stream>>>(Gb, HINb, RHb, HINf, 128, Wz2c, bz2, Wh2c, bh2, CX2f, nullptr, Nn);
    // CX2f holds x2 (fp32)

    // ================= layer 3 (fp32, D=64) =================
    float* H3  = X0f;
    float* XP3 = X0f + (size_t)Nn * 64;
    float* G3  = X0f + (size_t)Nn * 128;
    float* R3  = X0f + (size_t)Nn * 192;
    gemm_k<<<dim3(1, rb), blk, 0, stream>>>(CX2f, 128, nullptr, 0, Wp3, bp3, H3, Nn, 64, 0);
    gemm_k<<<dim3(1, rb), blk, 0, stream>>>(CX2f, 128, nullptr, 0, W3, nullptr, XP3, Nn, 64, 0);
    alpha_k<<<(Nn + 255) / 256, blk, 0, stream>>>(XP3, as3, ad3, AS, AD, Nn, 1, 64);
    {
        long waves = (Nn + 3) / 4;  // lpn=16, npw=4
        gat_gather<<<(int)((waves * 64 + 255) / 256), blk, 0, stream>>>(ioff, csr, XP3, AS, AD, b3, G3, Nn, 1, 64, 0);
    }
    gemm_k<<<dim3(1, rb), blk, 0, stream>>>(G3, 64, H3, 64, Wr3, br3, R3, Nn, 64, 1);
    gru_fused_k<<<dim3(1, rb), blk, 0, stream>>>(G3, H3, R3, 64, Wz3, bz3, Wh3, bh3, (float*)d_out, Nn);
}